// Round 1
// baseline (1313.008 us; speedup 1.0000x reference)
//
#include <hip/hip_runtime.h>

#define N_NODES 50000
#define N_EDGES_C 25000
#define NNZ_C 400000

typedef __bf16 bf16;
typedef __bf16 bf16x8 __attribute__((ext_vector_type(8)));
typedef __bf16 bf16x4 __attribute__((ext_vector_type(4)));
typedef float f32x4 __attribute__((ext_vector_type(4)));

// ---------------- CSR build ----------------
__global__ void hist_kernel(const int* __restrict__ vtx, const int* __restrict__ edg,
                            int* __restrict__ cntV, int* __restrict__ cntE, int nnz) {
  int i = blockIdx.x * blockDim.x + threadIdx.x;
  if (i < nnz) {
    atomicAdd(&cntV[vtx[i]], 1);
    atomicAdd(&cntE[edg[i]], 1);
  }
}

__global__ void exscan_kernel(const int* __restrict__ cnt, int* __restrict__ off, int n) {
  __shared__ int part[1024];
  const int t = threadIdx.x;
  const int per = (n + 1023) / 1024;
  const int beg = t * per;
  const int end = min(beg + per, n);
  int s = 0;
  for (int i = beg; i < end; ++i) s += cnt[i];
  part[t] = s;
  __syncthreads();
  for (int d = 1; d < 1024; d <<= 1) {
    int x = (t >= d) ? part[t - d] : 0;
    __syncthreads();
    part[t] += x;
    __syncthreads();
  }
  int run = (t > 0) ? part[t - 1] : 0;
  for (int i = beg; i < end; ++i) { off[i] = run; run += cnt[i]; }
  if (t == 1023) off[n] = part[1023];
}

__global__ void scatter_kernel(const int* __restrict__ vtx, const int* __restrict__ edg,
                               const int* __restrict__ eoff, const int* __restrict__ voff,
                               int* __restrict__ curE, int* __restrict__ curV,
                               int* __restrict__ evtx, int* __restrict__ vedg, int nnz) {
  int i = blockIdx.x * blockDim.x + threadIdx.x;
  if (i < nnz) {
    int e = edg[i], v = vtx[i];
    int p = atomicAdd(&curE[e], 1);
    evtx[eoff[e] + p] = v;
    int q = atomicAdd(&curV[v], 1);
    vedg[voff[v] + q] = e;
  }
}

// ---------------- conversions ----------------
__global__ void convert_f2b(const float* __restrict__ in, bf16* __restrict__ out, size_t n) {
  size_t i = ((size_t)blockIdx.x * blockDim.x + threadIdx.x) * 4;
  if (i >= n) return;
  float4 v = *(const float4*)(in + i);
  bf16x4 o;
  o[0] = (bf16)v.x; o[1] = (bf16)v.y; o[2] = (bf16)v.z; o[3] = (bf16)v.w;
  *(bf16x4*)(out + i) = o;
}

// Wt[n][k] = (n < N) ? W[k][n] : 0  for n in [0, NtRows)
__global__ void transpose_w(const float* __restrict__ W, bf16* __restrict__ Wt,
                            int K, int N, int NtRows) {
  int k = blockIdx.x * blockDim.x + threadIdx.x;
  if (k >= K) return;
  for (int n = 0; n < NtRows; ++n)
    Wt[(size_t)n * K + k] = (n < N) ? (bf16)W[(size_t)k * N + n] : (bf16)0.0f;
}

// ---------------- GEMM: C[M][Nstore] = A[M][K](bf16) @ B[n][K](bf16, row n = col n) ----------------
__global__ __launch_bounds__(256) void gemm_bf16_kernel(
    const bf16* __restrict__ A, const bf16* __restrict__ B,
    float* __restrict__ C, int M, int K, int ldC, int Nstore) {
  __shared__ bf16 Al[128][40];  // +8 pad: row stride 80B -> ~2-way bank alias (free)
  __shared__ bf16 Bl[128][40];
  const int t = threadIdx.x;
  const int m0 = blockIdx.x * 128;
  const int n0 = blockIdx.y * 128;
  const int w = t >> 6, lane = t & 63;
  const int wr = w >> 1, wc = w & 1;
  const int lr = lane & 15, lk = (lane >> 4) << 3;

  f32x4 acc[4][4];
#pragma unroll
  for (int m = 0; m < 4; ++m)
#pragma unroll
    for (int n = 0; n < 4; ++n) acc[m][n] = (f32x4){0.f, 0.f, 0.f, 0.f};

  const int rA = t >> 2;          // 0..63
  const int sg = (t & 3) << 3;    // k element offset 0,8,16,24

  for (int kk = 0; kk < K; kk += 32) {
#pragma unroll
    for (int p = 0; p < 2; ++p) {
      int r = rA + p * 64;
      int gm = m0 + r;
      uint4 av = {0u, 0u, 0u, 0u};
      if (gm < M) av = *(const uint4*)(A + (size_t)gm * K + kk + sg);
      *(uint4*)(&Al[r][sg]) = av;
      uint4 bv = *(const uint4*)(B + (size_t)(n0 + r) * K + kk + sg);
      *(uint4*)(&Bl[r][sg]) = bv;
    }
    __syncthreads();
    bf16x8 af[4], bfr[4];
#pragma unroll
    for (int m = 0; m < 4; ++m) af[m] = *(const bf16x8*)(&Al[wr * 64 + m * 16 + lr][lk]);
#pragma unroll
    for (int n = 0; n < 4; ++n) bfr[n] = *(const bf16x8*)(&Bl[wc * 64 + n * 16 + lr][lk]);
#pragma unroll
    for (int m = 0; m < 4; ++m)
#pragma unroll
      for (int n = 0; n < 4; ++n)
        acc[m][n] = __builtin_amdgcn_mfma_f32_16x16x32_bf16(af[m], bfr[n], acc[m][n], 0, 0, 0);
    __syncthreads();
  }

  const int cr = (lane >> 4) << 2;  // C/D: col = lane&15, row = (lane>>4)*4 + i
  const int cc = lane & 15;
#pragma unroll
  for (int m = 0; m < 4; ++m) {
#pragma unroll
    for (int n = 0; n < 4; ++n) {
      int gc = n0 + wc * 64 + n * 16 + cc;
      if (gc >= Nstore) continue;
#pragma unroll
      for (int i = 0; i < 4; ++i) {
        int gr = m0 + wr * 64 + m * 16 + cr + i;
        if (gr < M) C[(size_t)gr * ldC + gc] = acc[m][n][i];
      }
    }
  }
}

// ---------------- edge aggregation: Xe[e] = (mean over incidences) * degE[e] ----------------
__global__ void edge_agg_kernel(const float* __restrict__ Y, int ldY,
                                const int* __restrict__ eoff, const int* __restrict__ evtx,
                                const float* __restrict__ degE,
                                float* __restrict__ Xe, int ldXe, int C) {
  const int e = blockIdx.x;
  const int beg = eoff[e], end = eoff[e + 1];
  const int cnt = end - beg;
  const float scale = (cnt > 0) ? degE[e] / (float)cnt : 0.f;
  const int c0 = threadIdx.x;
  const int c1 = threadIdx.x + blockDim.x;
  float a0 = 0.f, a1 = 0.f;
  __shared__ int sidx[256];
  for (int base = beg; base < end; base += blockDim.x) {
    const int nb = min((int)blockDim.x, end - base);
    __syncthreads();
    if ((int)threadIdx.x < nb) sidx[threadIdx.x] = evtx[base + threadIdx.x];
    __syncthreads();
    for (int j = 0; j < nb; ++j) {
      const float* row = Y + (size_t)sidx[j] * ldY;
      if (c0 < C) a0 += row[c0];
      if (c1 < C) a1 += row[c1];
    }
  }
  if (c0 < C) Xe[(size_t)e * ldXe + c0] = a0 * scale;
  if (c1 < C) Xe[(size_t)e * ldXe + c1] = a1 * scale;
}

// ---------------- vertex aggregation: out[v] = (sum) * degV[v], optional relu, bf16 or f32 out ----------------
template <int BF16OUT>
__global__ void vtx_agg_kernel(const float* __restrict__ Xe, int ldXe,
                               const int* __restrict__ voff, const int* __restrict__ vedg,
                               const float* __restrict__ degV,
                               float* __restrict__ outF, bf16* __restrict__ outB,
                               int ldO, int C, int doRelu) {
  const int v = blockIdx.x;
  const int beg = voff[v], end = voff[v + 1];
  const float dv = degV[v];
  const int c0 = threadIdx.x;
  const int c1 = threadIdx.x + blockDim.x;
  float a0 = 0.f, a1 = 0.f;
  __shared__ int sidx[256];
  for (int base = beg; base < end; base += blockDim.x) {
    const int nb = min((int)blockDim.x, end - base);
    __syncthreads();
    if ((int)threadIdx.x < nb) sidx[threadIdx.x] = vedg[base + threadIdx.x];
    __syncthreads();
    for (int j = 0; j < nb; ++j) {
      const float* row = Xe + (size_t)sidx[j] * ldXe;
      if (c0 < C) a0 += row[c0];
      if (c1 < C) a1 += row[c1];
    }
  }
  a0 *= dv; a1 *= dv;
  if (doRelu) { a0 = fmaxf(a0, 0.f); a1 = fmaxf(a1, 0.f); }
  if (BF16OUT) {
    if (c0 < C) outB[(size_t)v * ldO + c0] = (bf16)a0;
    if (c1 < C) outB[(size_t)v * ldO + c1] = (bf16)a1;
  } else {
    if (c0 < C) outF[(size_t)v * ldO + c0] = a0;
    if (c1 < C) outF[(size_t)v * ldO + c1] = a1;
  }
}

// ---------------- log_softmax over rows of C elements (wave per row) ----------------
__global__ void log_softmax_kernel(const float* __restrict__ Z, float* __restrict__ out,
                                   int C, int nrows) {
  const int row = blockIdx.x * (blockDim.x >> 6) + (threadIdx.x >> 6);
  const int lane = threadIdx.x & 63;
  if (row >= nrows) return;
  float v = (lane < C) ? Z[(size_t)row * C + lane] : -3.4e38f;
  float m = v;
#pragma unroll
  for (int o = 32; o > 0; o >>= 1) m = fmaxf(m, __shfl_xor(m, o));
  float ex = (lane < C) ? expf(v - m) : 0.f;
  float s = ex;
#pragma unroll
  for (int o = 32; o > 0; o >>= 1) s += __shfl_xor(s, o);
  float ls = logf(s);
  if (lane < C) out[(size_t)row * C + lane] = v - m - ls;
}

extern "C" void kernel_launch(void* const* d_in, const int* in_sizes, int n_in,
                              void* d_out, int out_size, void* d_ws, size_t ws_size,
                              hipStream_t stream) {
  (void)in_sizes; (void)n_in; (void)out_size; (void)ws_size;
  const float* X = (const float*)d_in[0];
  const int* vertex = (const int*)d_in[1];
  const int* edges = (const int*)d_in[2];
  const float* W1 = (const float*)d_in[3];
  const float* W2 = (const float*)d_in[4];
  const float* Wout = (const float*)d_in[5];
  const float* degE = (const float*)d_in[6];
  const float* degV = (const float*)d_in[7];
  float* out = (float*)d_out;

  char* ws = (char*)d_ws;
  size_t off = 0;
  auto alloc = [&](size_t bytes) -> void* {
    void* p = ws + off;
    off += (bytes + 255) & ~(size_t)255;
    return p;
  };
  bf16* Xb   = (bf16*)alloc((size_t)N_NODES * 512 * sizeof(bf16));
  float* Y   = (float*)alloc((size_t)N_NODES * 512 * sizeof(float));
  float* Xe  = (float*)alloc((size_t)N_EDGES_C * 512 * sizeof(float));
  bf16* Wt   = (bf16*)alloc((size_t)512 * 512 * sizeof(bf16));
  int* eoff  = (int*)alloc((N_EDGES_C + 1) * sizeof(int));
  int* voff  = (int*)alloc((N_NODES + 1) * sizeof(int));
  int* evtx  = (int*)alloc((size_t)NNZ_C * sizeof(int));
  int* vedg  = (int*)alloc((size_t)NNZ_C * sizeof(int));
  int* cntE  = (int*)alloc(N_EDGES_C * sizeof(int));
  int* cntV  = (int*)alloc(N_NODES * sizeof(int));
  int* curE  = (int*)alloc(N_EDGES_C * sizeof(int));
  int* curV  = (int*)alloc(N_NODES * sizeof(int));

  hipMemsetAsync(cntE, 0, N_EDGES_C * sizeof(int), stream);
  hipMemsetAsync(cntV, 0, N_NODES * sizeof(int), stream);
  hipMemsetAsync(curE, 0, N_EDGES_C * sizeof(int), stream);
  hipMemsetAsync(curV, 0, N_NODES * sizeof(int), stream);

  hist_kernel<<<(NNZ_C + 255) / 256, 256, 0, stream>>>(vertex, edges, cntV, cntE, NNZ_C);
  exscan_kernel<<<1, 1024, 0, stream>>>(cntE, eoff, N_EDGES_C);
  exscan_kernel<<<1, 1024, 0, stream>>>(cntV, voff, N_NODES);
  scatter_kernel<<<(NNZ_C + 255) / 256, 256, 0, stream>>>(vertex, edges, eoff, voff,
                                                          curE, curV, evtx, vedg, NNZ_C);

  // X -> bf16
  convert_f2b<<<(N_NODES * 512 / 4 + 255) / 256, 256, 0, stream>>>(X, Xb, (size_t)N_NODES * 512);

  const int MB = (N_NODES + 127) / 128;

  // ---- layer 1 ----
  transpose_w<<<2, 256, 0, stream>>>(W1, Wt, 512, 512, 512);
  {
    dim3 g(MB, 4);
    gemm_bf16_kernel<<<g, 256, 0, stream>>>(Xb, Wt, Y, N_NODES, 512, 512, 512);
  }
  edge_agg_kernel<<<N_EDGES_C, 256, 0, stream>>>(Y, 512, eoff, evtx, degE, Xe, 512, 512);
  vtx_agg_kernel<1><<<N_NODES, 256, 0, stream>>>(Xe, 512, voff, vedg, degV, nullptr, Xb, 512, 512, 1);

  // ---- layer 2 ----
  transpose_w<<<2, 256, 0, stream>>>(W2, Wt, 512, 512, 512);
  {
    dim3 g(MB, 4);
    gemm_bf16_kernel<<<g, 256, 0, stream>>>(Xb, Wt, Y, N_NODES, 512, 512, 512);
  }
  edge_agg_kernel<<<N_EDGES_C, 256, 0, stream>>>(Y, 512, eoff, evtx, degE, Xe, 512, 512);
  vtx_agg_kernel<1><<<N_NODES, 256, 0, stream>>>(Xe, 512, voff, vedg, degV, nullptr, Xb, 512, 512, 1);

  // ---- layer 3 (C=40, pad Wt to 128 rows of zeros) ----
  transpose_w<<<2, 256, 0, stream>>>(Wout, Wt, 512, 40, 128);
  {
    dim3 g(MB, 1);
    gemm_bf16_kernel<<<g, 256, 0, stream>>>(Xb, Wt, Y, N_NODES, 512, 40, 40);
  }
  edge_agg_kernel<<<N_EDGES_C, 64, 0, stream>>>(Y, 40, eoff, evtx, degE, Xe, 40, 40);
  vtx_agg_kernel<0><<<N_NODES, 64, 0, stream>>>(Xe, 40, voff, vedg, degV, Y, nullptr, 40, 40, 0);

  log_softmax_kernel<<<N_NODES / 4, 256, 0, stream>>>(Y, out, 40, N_NODES);
}

// Round 2
// 883.152 us; speedup vs baseline: 1.4867x; 1.4867x over previous
//
#include <hip/hip_runtime.h>

#define N_NODES 50000
#define N_EDGES_C 25000
#define NNZ_C 400000

typedef __bf16 bf16;
typedef __bf16 bf16x8 __attribute__((ext_vector_type(8)));
typedef __bf16 bf16x4 __attribute__((ext_vector_type(4)));
typedef __bf16 bf16x2 __attribute__((ext_vector_type(2)));
typedef float f32x4 __attribute__((ext_vector_type(4)));

// ---------------- CSR build ----------------
__global__ void hist_kernel(const int* __restrict__ vtx, const int* __restrict__ edg,
                            int* __restrict__ cntV, int* __restrict__ cntE, int nnz) {
  int i = blockIdx.x * blockDim.x + threadIdx.x;
  if (i < nnz) {
    atomicAdd(&cntV[vtx[i]], 1);
    atomicAdd(&cntE[edg[i]], 1);
  }
}

__global__ void exscan_kernel(const int* __restrict__ cnt, int* __restrict__ off, int n) {
  __shared__ int part[1024];
  const int t = threadIdx.x;
  const int per = (n + 1023) / 1024;
  const int beg = t * per;
  const int end = min(beg + per, n);
  int s = 0;
  for (int i = beg; i < end; ++i) s += cnt[i];
  part[t] = s;
  __syncthreads();
  for (int d = 1; d < 1024; d <<= 1) {
    int x = (t >= d) ? part[t - d] : 0;
    __syncthreads();
    part[t] += x;
    __syncthreads();
  }
  int run = (t > 0) ? part[t - 1] : 0;
  for (int i = beg; i < end; ++i) { off[i] = run; run += cnt[i]; }
  if (t == 1023) off[n] = part[1023];
}

__global__ void scatter_kernel(const int* __restrict__ vtx, const int* __restrict__ edg,
                               const int* __restrict__ eoff, const int* __restrict__ voff,
                               int* __restrict__ curE, int* __restrict__ curV,
                               int* __restrict__ evtx, int* __restrict__ vedg, int nnz) {
  int i = blockIdx.x * blockDim.x + threadIdx.x;
  if (i < nnz) {
    int e = edg[i], v = vtx[i];
    int p = atomicAdd(&curE[e], 1);
    evtx[eoff[e] + p] = v;
    int q = atomicAdd(&curV[v], 1);
    vedg[voff[v] + q] = e;
  }
}

// ---------------- conversions ----------------
__global__ void convert_f2b(const float* __restrict__ in, bf16* __restrict__ out, size_t n) {
  size_t i = ((size_t)blockIdx.x * blockDim.x + threadIdx.x) * 4;
  if (i >= n) return;
  float4 v = *(const float4*)(in + i);
  bf16x4 o;
  o[0] = (bf16)v.x; o[1] = (bf16)v.y; o[2] = (bf16)v.z; o[3] = (bf16)v.w;
  *(bf16x4*)(out + i) = o;
}

// Wt[n][k] = (n < N) ? W[k][n] : 0  for n in [0, NtRows)
__global__ void transpose_w(const float* __restrict__ W, bf16* __restrict__ Wt,
                            int K, int N, int NtRows) {
  int k = blockIdx.x * blockDim.x + threadIdx.x;
  if (k >= K) return;
  for (int n = 0; n < NtRows; ++n)
    Wt[(size_t)n * K + k] = (n < N) ? (bf16)W[(size_t)k * N + n] : (bf16)0.0f;
}

// ---------------- GEMM: C[M][*] = A[M][K](bf16) @ B[n][K](bf16, row n = col n) ----------------
template <int BF16OUT>
__global__ __launch_bounds__(256) void gemm_bf16_kernel(
    const bf16* __restrict__ A, const bf16* __restrict__ B,
    float* __restrict__ Cf, bf16* __restrict__ Cb, int M, int K, int ldC, int Nstore) {
  __shared__ bf16 Al[128][40];  // +8 pad
  __shared__ bf16 Bl[128][40];
  const int t = threadIdx.x;
  const int m0 = blockIdx.x * 128;
  const int n0 = blockIdx.y * 128;
  const int w = t >> 6, lane = t & 63;
  const int wr = w >> 1, wc = w & 1;
  const int lr = lane & 15, lk = (lane >> 4) << 3;

  f32x4 acc[4][4];
#pragma unroll
  for (int m = 0; m < 4; ++m)
#pragma unroll
    for (int n = 0; n < 4; ++n) acc[m][n] = (f32x4){0.f, 0.f, 0.f, 0.f};

  const int rA = t >> 2;
  const int sg = (t & 3) << 3;

  for (int kk = 0; kk < K; kk += 32) {
#pragma unroll
    for (int p = 0; p < 2; ++p) {
      int r = rA + p * 64;
      int gm = m0 + r;
      uint4 av = {0u, 0u, 0u, 0u};
      if (gm < M) av = *(const uint4*)(A + (size_t)gm * K + kk + sg);
      *(uint4*)(&Al[r][sg]) = av;
      uint4 bv = *(const uint4*)(B + (size_t)(n0 + r) * K + kk + sg);
      *(uint4*)(&Bl[r][sg]) = bv;
    }
    __syncthreads();
    bf16x8 af[4], bfr[4];
#pragma unroll
    for (int m = 0; m < 4; ++m) af[m] = *(const bf16x8*)(&Al[wr * 64 + m * 16 + lr][lk]);
#pragma unroll
    for (int n = 0; n < 4; ++n) bfr[n] = *(const bf16x8*)(&Bl[wc * 64 + n * 16 + lr][lk]);
#pragma unroll
    for (int m = 0; m < 4; ++m)
#pragma unroll
      for (int n = 0; n < 4; ++n)
        acc[m][n] = __builtin_amdgcn_mfma_f32_16x16x32_bf16(af[m], bfr[n], acc[m][n], 0, 0, 0);
    __syncthreads();
  }

  const int cr = (lane >> 4) << 2;  // C/D: col = lane&15, row = (lane>>4)*4 + i
  const int cc = lane & 15;
#pragma unroll
  for (int m = 0; m < 4; ++m) {
#pragma unroll
    for (int n = 0; n < 4; ++n) {
      int gc = n0 + wc * 64 + n * 16 + cc;
      if (gc >= Nstore) continue;
#pragma unroll
      for (int i = 0; i < 4; ++i) {
        int gr = m0 + wr * 64 + m * 16 + cr + i;
        if (gr < M) {
          if (BF16OUT) Cb[(size_t)gr * ldC + gc] = (bf16)acc[m][n][i];
          else         Cf[(size_t)gr * ldC + gc] = acc[m][n][i];
        }
      }
    }
  }
}

// ---------------- edge aggregation (bf16 in/out, C=512, block=256) ----------------
__global__ __launch_bounds__(256) void edge_agg_bf16(
    const bf16* __restrict__ Y, const int* __restrict__ eoff, const int* __restrict__ evtx,
    const float* __restrict__ degE, bf16* __restrict__ Xe) {
  const int e = blockIdx.x;
  const int beg = eoff[e], end = eoff[e + 1];
  const int cnt = end - beg;
  const float scale = (cnt > 0) ? degE[e] / (float)cnt : 0.f;
  const int t = threadIdx.x;
  float a0 = 0.f, a1 = 0.f;
  __shared__ int sidx[256];
  for (int base = beg; base < end; base += 256) {
    const int nb = min(256, end - base);
    __syncthreads();
    if (t < nb) sidx[t] = evtx[base + t];
    __syncthreads();
    int j = 0;
    for (; j + 1 < nb; j += 2) {
      bf16x2 v0 = *(const bf16x2*)(Y + (size_t)sidx[j] * 512 + 2 * t);
      bf16x2 v1 = *(const bf16x2*)(Y + (size_t)sidx[j + 1] * 512 + 2 * t);
      a0 += (float)v0[0] + (float)v1[0];
      a1 += (float)v0[1] + (float)v1[1];
    }
    if (j < nb) {
      bf16x2 v0 = *(const bf16x2*)(Y + (size_t)sidx[j] * 512 + 2 * t);
      a0 += (float)v0[0];
      a1 += (float)v0[1];
    }
  }
  bf16x2 o;
  o[0] = (bf16)(a0 * scale);
  o[1] = (bf16)(a1 * scale);
  *(bf16x2*)(Xe + (size_t)e * 512 + 2 * t) = o;
}

// ---------------- vertex aggregation (bf16 in/out, relu, C=512, block=256) ----------------
__global__ __launch_bounds__(256) void vtx_agg_bf16(
    const bf16* __restrict__ Xe, const int* __restrict__ voff, const int* __restrict__ vedg,
    const float* __restrict__ degV, bf16* __restrict__ outB) {
  const int v = blockIdx.x;
  const int beg = voff[v], end = voff[v + 1];
  const float dv = degV[v];
  const int t = threadIdx.x;
  float a0 = 0.f, a1 = 0.f;
  __shared__ int sidx[256];
  for (int base = beg; base < end; base += 256) {
    const int nb = min(256, end - base);
    __syncthreads();
    if (t < nb) sidx[t] = vedg[base + t];
    __syncthreads();
    int j = 0;
    for (; j + 1 < nb; j += 2) {
      bf16x2 v0 = *(const bf16x2*)(Xe + (size_t)sidx[j] * 512 + 2 * t);
      bf16x2 v1 = *(const bf16x2*)(Xe + (size_t)sidx[j + 1] * 512 + 2 * t);
      a0 += (float)v0[0] + (float)v1[0];
      a1 += (float)v0[1] + (float)v1[1];
    }
    if (j < nb) {
      bf16x2 v0 = *(const bf16x2*)(Xe + (size_t)sidx[j] * 512 + 2 * t);
      a0 += (float)v0[0];
      a1 += (float)v0[1];
    }
  }
  a0 = fmaxf(a0 * dv, 0.f);
  a1 = fmaxf(a1 * dv, 0.f);
  bf16x2 o;
  o[0] = (bf16)a0;
  o[1] = (bf16)a1;
  *(bf16x2*)(outB + (size_t)v * 512 + 2 * t) = o;
}

// ---------------- edge aggregation f32 (layer 3, C=40, block=64) ----------------
__global__ void edge_agg_f32(const float* __restrict__ Y, int ldY,
                             const int* __restrict__ eoff, const int* __restrict__ evtx,
                             const float* __restrict__ degE,
                             float* __restrict__ Xe, int ldXe, int C) {
  const int e = blockIdx.x;
  const int beg = eoff[e], end = eoff[e + 1];
  const int cnt = end - beg;
  const float scale = (cnt > 0) ? degE[e] / (float)cnt : 0.f;
  const int c0 = threadIdx.x;
  float a0 = 0.f;
  __shared__ int sidx[64];
  for (int base = beg; base < end; base += blockDim.x) {
    const int nb = min((int)blockDim.x, end - base);
    __syncthreads();
    if ((int)threadIdx.x < nb) sidx[threadIdx.x] = evtx[base + threadIdx.x];
    __syncthreads();
    for (int j = 0; j < nb; ++j) {
      if (c0 < C) a0 += Y[(size_t)sidx[j] * ldY + c0];
    }
  }
  if (c0 < C) Xe[(size_t)e * ldXe + c0] = a0 * scale;
}

// ---------------- final vertex aggregation + log_softmax fused (C=40, block=64=1 wave) ----------------
__global__ void vtx_agg_lsm(const float* __restrict__ Xe, int ldXe,
                            const int* __restrict__ voff, const int* __restrict__ vedg,
                            const float* __restrict__ degV,
                            float* __restrict__ out, int C) {
  const int v = blockIdx.x;
  const int beg = voff[v], end = voff[v + 1];
  const float dv = degV[v];
  const int lane = threadIdx.x;  // 64 = one wave
  float a0 = 0.f;
  __shared__ int sidx[64];
  for (int base = beg; base < end; base += 64) {
    const int nb = min(64, end - base);
    __syncthreads();
    if (lane < nb) sidx[lane] = vedg[base + lane];
    __syncthreads();
    for (int j = 0; j < nb; ++j) {
      if (lane < C) a0 += Xe[(size_t)sidx[j] * ldXe + lane];
    }
  }
  a0 *= dv;
  float val = (lane < C) ? a0 : -3.4e38f;
  float m = val;
#pragma unroll
  for (int o = 32; o > 0; o >>= 1) m = fmaxf(m, __shfl_xor(m, o));
  float ex = (lane < C) ? expf(val - m) : 0.f;
  float s = ex;
#pragma unroll
  for (int o = 32; o > 0; o >>= 1) s += __shfl_xor(s, o);
  float ls = logf(s);
  if (lane < C) out[(size_t)v * C + lane] = val - m - ls;
}

extern "C" void kernel_launch(void* const* d_in, const int* in_sizes, int n_in,
                              void* d_out, int out_size, void* d_ws, size_t ws_size,
                              hipStream_t stream) {
  (void)in_sizes; (void)n_in; (void)out_size; (void)ws_size;
  const float* X = (const float*)d_in[0];
  const int* vertex = (const int*)d_in[1];
  const int* edges = (const int*)d_in[2];
  const float* W1 = (const float*)d_in[3];
  const float* W2 = (const float*)d_in[4];
  const float* Wout = (const float*)d_in[5];
  const float* degE = (const float*)d_in[6];
  const float* degV = (const float*)d_in[7];
  float* out = (float*)d_out;

  char* ws = (char*)d_ws;
  size_t off = 0;
  auto alloc = [&](size_t bytes) -> void* {
    void* p = ws + off;
    off += (bytes + 255) & ~(size_t)255;
    return p;
  };
  bf16* Xb  = (bf16*)alloc((size_t)N_NODES * 512 * sizeof(bf16));   // GEMM A / layer input
  bf16* Yb  = (bf16*)alloc((size_t)N_NODES * 512 * sizeof(bf16));   // GEMM out (layers 1,2)
  bf16* XeB = (bf16*)alloc((size_t)N_EDGES_C * 512 * sizeof(bf16)); // edge feats (layers 1,2)
  float* Y40  = (float*)alloc((size_t)N_NODES * 64 * sizeof(float));   // layer-3 GEMM out
  float* Xe40 = (float*)alloc((size_t)N_EDGES_C * 64 * sizeof(float)); // layer-3 edge feats
  bf16* Wt  = (bf16*)alloc((size_t)512 * 512 * sizeof(bf16));
  int* eoff = (int*)alloc((N_EDGES_C + 1) * sizeof(int));
  int* voff = (int*)alloc((N_NODES + 1) * sizeof(int));
  int* evtx = (int*)alloc((size_t)NNZ_C * sizeof(int));
  int* vedg = (int*)alloc((size_t)NNZ_C * sizeof(int));
  int* cntE = (int*)alloc(N_EDGES_C * sizeof(int));
  int* cntV = (int*)alloc(N_NODES * sizeof(int));
  int* curE = (int*)alloc(N_EDGES_C * sizeof(int));
  int* curV = (int*)alloc(N_NODES * sizeof(int));

  hipMemsetAsync(cntE, 0, N_EDGES_C * sizeof(int), stream);
  hipMemsetAsync(cntV, 0, N_NODES * sizeof(int), stream);
  hipMemsetAsync(curE, 0, N_EDGES_C * sizeof(int), stream);
  hipMemsetAsync(curV, 0, N_NODES * sizeof(int), stream);

  hist_kernel<<<(NNZ_C + 255) / 256, 256, 0, stream>>>(vertex, edges, cntV, cntE, NNZ_C);
  exscan_kernel<<<1, 1024, 0, stream>>>(cntE, eoff, N_EDGES_C);
  exscan_kernel<<<1, 1024, 0, stream>>>(cntV, voff, N_NODES);
  scatter_kernel<<<(NNZ_C + 255) / 256, 256, 0, stream>>>(vertex, edges, eoff, voff,
                                                          curE, curV, evtx, vedg, NNZ_C);

  convert_f2b<<<(N_NODES * 512 / 4 + 255) / 256, 256, 0, stream>>>(X, Xb, (size_t)N_NODES * 512);

  const int MB = (N_NODES + 127) / 128;

  // ---- layer 1 ----
  transpose_w<<<2, 256, 0, stream>>>(W1, Wt, 512, 512, 512);
  {
    dim3 g(MB, 4);
    gemm_bf16_kernel<1><<<g, 256, 0, stream>>>(Xb, Wt, nullptr, Yb, N_NODES, 512, 512, 512);
  }
  edge_agg_bf16<<<N_EDGES_C, 256, 0, stream>>>(Yb, eoff, evtx, degE, XeB);
  vtx_agg_bf16<<<N_NODES, 256, 0, stream>>>(XeB, voff, vedg, degV, Xb);

  // ---- layer 2 ----
  transpose_w<<<2, 256, 0, stream>>>(W2, Wt, 512, 512, 512);
  {
    dim3 g(MB, 4);
    gemm_bf16_kernel<1><<<g, 256, 0, stream>>>(Xb, Wt, nullptr, Yb, N_NODES, 512, 512, 512);
  }
  edge_agg_bf16<<<N_EDGES_C, 256, 0, stream>>>(Yb, eoff, evtx, degE, XeB);
  vtx_agg_bf16<<<N_NODES, 256, 0, stream>>>(XeB, voff, vedg, degV, Xb);

  // ---- layer 3 (C=40) ----
  transpose_w<<<2, 256, 0, stream>>>(Wout, Wt, 512, 40, 128);
  {
    dim3 g(MB, 1);
    gemm_bf16_kernel<0><<<g, 256, 0, stream>>>(Xb, Wt, Y40, nullptr, N_NODES, 512, 40, 40);
  }
  edge_agg_f32<<<N_EDGES_C, 64, 0, stream>>>(Y40, 40, eoff, evtx, degE, Xe40, 40, 40);
  vtx_agg_lsm<<<N_NODES, 64, 0, stream>>>(Xe40, 40, voff, vedg, degV, out, 40);
}

// Round 3
// 708.171 us; speedup vs baseline: 1.8541x; 1.2471x over previous
//
#include <hip/hip_runtime.h>

#define N_NODES 50000
#define N_EDGES_C 25000
#define NNZ_C 400000

typedef __bf16 bf16;
typedef __bf16 bf16x8 __attribute__((ext_vector_type(8)));
typedef __bf16 bf16x4 __attribute__((ext_vector_type(4)));
typedef __bf16 bf16x2 __attribute__((ext_vector_type(2)));
typedef float f32x4 __attribute__((ext_vector_type(4)));

// ---------------- CSR build ----------------
__global__ void hist_kernel(const int* __restrict__ vtx, const int* __restrict__ edg,
                            int* __restrict__ cntV, int* __restrict__ cntE, int nnz) {
  int i = blockIdx.x * blockDim.x + threadIdx.x;
  if (i < nnz) {
    atomicAdd(&cntV[vtx[i]], 1);
    atomicAdd(&cntE[edg[i]], 1);
  }
}

__global__ void exscan_kernel(const int* __restrict__ cnt, int* __restrict__ off, int n) {
  __shared__ int part[1024];
  const int t = threadIdx.x;
  const int per = (n + 1023) / 1024;
  const int beg = t * per;
  const int end = min(beg + per, n);
  int s = 0;
  for (int i = beg; i < end; ++i) s += cnt[i];
  part[t] = s;
  __syncthreads();
  for (int d = 1; d < 1024; d <<= 1) {
    int x = (t >= d) ? part[t - d] : 0;
    __syncthreads();
    part[t] += x;
    __syncthreads();
  }
  int run = (t > 0) ? part[t - 1] : 0;
  for (int i = beg; i < end; ++i) { off[i] = run; run += cnt[i]; }
  if (t == 1023) off[n] = part[1023];
}

__global__ void scatter_kernel(const int* __restrict__ vtx, const int* __restrict__ edg,
                               const int* __restrict__ eoff, const int* __restrict__ voff,
                               int* __restrict__ curE, int* __restrict__ curV,
                               int* __restrict__ evtx, int* __restrict__ vedg, int nnz) {
  int i = blockIdx.x * blockDim.x + threadIdx.x;
  if (i < nnz) {
    int e = edg[i], v = vtx[i];
    int p = atomicAdd(&curE[e], 1);
    evtx[eoff[e] + p] = v;
    int q = atomicAdd(&curV[v], 1);
    vedg[voff[v] + q] = e;
  }
}

// ---------------- conversions ----------------
__global__ void convert_f2b(const float* __restrict__ in, bf16* __restrict__ out, size_t n) {
  size_t i = ((size_t)blockIdx.x * blockDim.x + threadIdx.x) * 4;
  if (i >= n) return;
  float4 v = *(const float4*)(in + i);
  bf16x4 o;
  o[0] = (bf16)v.x; o[1] = (bf16)v.y; o[2] = (bf16)v.z; o[3] = (bf16)v.w;
  *(bf16x4*)(out + i) = o;
}

// Wt[n][k] = (n < N) ? W[k][n] : 0, fully parallel: one thread per output element
__global__ void transpose_w(const float* __restrict__ W, bf16* __restrict__ Wt,
                            int K, int N, int NtRows) {
  int idx = blockIdx.x * blockDim.x + threadIdx.x;
  int total = NtRows * K;
  if (idx >= total) return;
  int n = idx / K;
  int k = idx - n * K;
  Wt[idx] = (n < N) ? (bf16)W[(size_t)k * N + n] : (bf16)0.0f;
}

// ---------------- GEMM: C[M][*] = A[M][K](bf16) @ B[n][K](bf16, row n = col n) ----------------
template <int BF16OUT>
__global__ __launch_bounds__(256) void gemm_bf16_kernel(
    const bf16* __restrict__ A, const bf16* __restrict__ B,
    float* __restrict__ Cf, bf16* __restrict__ Cb, int M, int K, int ldC, int Nstore) {
  __shared__ bf16 Al[128][40];  // +8 pad
  __shared__ bf16 Bl[128][40];
  const int t = threadIdx.x;
  const int m0 = blockIdx.x * 128;
  const int n0 = blockIdx.y * 128;
  const int w = t >> 6, lane = t & 63;
  const int wr = w >> 1, wc = w & 1;
  const int lr = lane & 15, lk = (lane >> 4) << 3;

  f32x4 acc[4][4];
#pragma unroll
  for (int m = 0; m < 4; ++m)
#pragma unroll
    for (int n = 0; n < 4; ++n) acc[m][n] = (f32x4){0.f, 0.f, 0.f, 0.f};

  const int rA = t >> 2;
  const int sg = (t & 3) << 3;

  for (int kk = 0; kk < K; kk += 32) {
#pragma unroll
    for (int p = 0; p < 2; ++p) {
      int r = rA + p * 64;
      int gm = m0 + r;
      uint4 av = {0u, 0u, 0u, 0u};
      if (gm < M) av = *(const uint4*)(A + (size_t)gm * K + kk + sg);
      *(uint4*)(&Al[r][sg]) = av;
      uint4 bv = *(const uint4*)(B + (size_t)(n0 + r) * K + kk + sg);
      *(uint4*)(&Bl[r][sg]) = bv;
    }
    __syncthreads();
    bf16x8 af[4], bfr[4];
#pragma unroll
    for (int m = 0; m < 4; ++m) af[m] = *(const bf16x8*)(&Al[wr * 64 + m * 16 + lr][lk]);
#pragma unroll
    for (int n = 0; n < 4; ++n) bfr[n] = *(const bf16x8*)(&Bl[wc * 64 + n * 16 + lr][lk]);
#pragma unroll
    for (int m = 0; m < 4; ++m)
#pragma unroll
      for (int n = 0; n < 4; ++n)
        acc[m][n] = __builtin_amdgcn_mfma_f32_16x16x32_bf16(af[m], bfr[n], acc[m][n], 0, 0, 0);
    __syncthreads();
  }

  const int cr = (lane >> 4) << 2;  // C/D: col = lane&15, row = (lane>>4)*4 + i
  const int cc = lane & 15;
#pragma unroll
  for (int m = 0; m < 4; ++m) {
#pragma unroll
    for (int n = 0; n < 4; ++n) {
      int gc = n0 + wc * 64 + n * 16 + cc;
      if (gc >= Nstore) continue;
#pragma unroll
      for (int i = 0; i < 4; ++i) {
        int gr = m0 + wr * 64 + m * 16 + cr + i;
        if (gr < M) {
          if (BF16OUT) Cb[(size_t)gr * ldC + gc] = (bf16)acc[m][n][i];
          else         Cf[(size_t)gr * ldC + gc] = acc[m][n][i];
        }
      }
    }
  }
}

// ---------------- edge aggregation (bf16 in/out, C=512, block=256) ----------------
__global__ __launch_bounds__(256) void edge_agg_bf16(
    const bf16* __restrict__ Y, const int* __restrict__ eoff, const int* __restrict__ evtx,
    const float* __restrict__ degE, bf16* __restrict__ Xe) {
  const int e = blockIdx.x;
  const int beg = eoff[e], end = eoff[e + 1];
  const int cnt = end - beg;
  const float scale = (cnt > 0) ? degE[e] / (float)cnt : 0.f;
  const int t = threadIdx.x;
  float a0 = 0.f, a1 = 0.f;
  __shared__ int sidx[256];
  for (int base = beg; base < end; base += 256) {
    const int nb = min(256, end - base);
    __syncthreads();
    if (t < nb) sidx[t] = evtx[base + t];
    __syncthreads();
    int j = 0;
    for (; j + 1 < nb; j += 2) {
      bf16x2 v0 = *(const bf16x2*)(Y + (size_t)sidx[j] * 512 + 2 * t);
      bf16x2 v1 = *(const bf16x2*)(Y + (size_t)sidx[j + 1] * 512 + 2 * t);
      a0 += (float)v0[0] + (float)v1[0];
      a1 += (float)v0[1] + (float)v1[1];
    }
    if (j < nb) {
      bf16x2 v0 = *(const bf16x2*)(Y + (size_t)sidx[j] * 512 + 2 * t);
      a0 += (float)v0[0];
      a1 += (float)v0[1];
    }
  }
  bf16x2 o;
  o[0] = (bf16)(a0 * scale);
  o[1] = (bf16)(a1 * scale);
  *(bf16x2*)(Xe + (size_t)e * 512 + 2 * t) = o;
}

// ---------------- vertex aggregation (bf16 in/out, relu, C=512, block=256) ----------------
__global__ __launch_bounds__(256) void vtx_agg_bf16(
    const bf16* __restrict__ Xe, const int* __restrict__ voff, const int* __restrict__ vedg,
    const float* __restrict__ degV, bf16* __restrict__ outB) {
  const int v = blockIdx.x;
  const int beg = voff[v], end = voff[v + 1];
  const float dv = degV[v];
  const int t = threadIdx.x;
  float a0 = 0.f, a1 = 0.f;
  __shared__ int sidx[256];
  for (int base = beg; base < end; base += 256) {
    const int nb = min(256, end - base);
    __syncthreads();
    if (t < nb) sidx[t] = vedg[base + t];
    __syncthreads();
    int j = 0;
    for (; j + 1 < nb; j += 2) {
      bf16x2 v0 = *(const bf16x2*)(Xe + (size_t)sidx[j] * 512 + 2 * t);
      bf16x2 v1 = *(const bf16x2*)(Xe + (size_t)sidx[j + 1] * 512 + 2 * t);
      a0 += (float)v0[0] + (float)v1[0];
      a1 += (float)v0[1] + (float)v1[1];
    }
    if (j < nb) {
      bf16x2 v0 = *(const bf16x2*)(Xe + (size_t)sidx[j] * 512 + 2 * t);
      a0 += (float)v0[0];
      a1 += (float)v0[1];
    }
  }
  a0 = fmaxf(a0 * dv, 0.f);
  a1 = fmaxf(a1 * dv, 0.f);
  bf16x2 o;
  o[0] = (bf16)a0;
  o[1] = (bf16)a1;
  *(bf16x2*)(outB + (size_t)v * 512 + 2 * t) = o;
}

// ---------------- edge aggregation f32 (layer 3, C=40, block=64) ----------------
__global__ void edge_agg_f32(const float* __restrict__ Y, int ldY,
                             const int* __restrict__ eoff, const int* __restrict__ evtx,
                             const float* __restrict__ degE,
                             float* __restrict__ Xe, int ldXe, int C) {
  const int e = blockIdx.x;
  const int beg = eoff[e], end = eoff[e + 1];
  const int cnt = end - beg;
  const float scale = (cnt > 0) ? degE[e] / (float)cnt : 0.f;
  const int c0 = threadIdx.x;
  float a0 = 0.f;
  __shared__ int sidx[64];
  for (int base = beg; base < end; base += blockDim.x) {
    const int nb = min((int)blockDim.x, end - base);
    __syncthreads();
    if ((int)threadIdx.x < nb) sidx[threadIdx.x] = evtx[base + threadIdx.x];
    __syncthreads();
    for (int j = 0; j < nb; ++j) {
      if (c0 < C) a0 += Y[(size_t)sidx[j] * ldY + c0];
    }
  }
  if (c0 < C) Xe[(size_t)e * ldXe + c0] = a0 * scale;
}

// ---------------- final vertex aggregation + log_softmax fused (C=40, block=64=1 wave) ----------------
__global__ void vtx_agg_lsm(const float* __restrict__ Xe, int ldXe,
                            const int* __restrict__ voff, const int* __restrict__ vedg,
                            const float* __restrict__ degV,
                            float* __restrict__ out, int C) {
  const int v = blockIdx.x;
  const int beg = voff[v], end = voff[v + 1];
  const float dv = degV[v];
  const int lane = threadIdx.x;  // 64 = one wave
  float a0 = 0.f;
  __shared__ int sidx[64];
  for (int base = beg; base < end; base += 64) {
    const int nb = min(64, end - base);
    __syncthreads();
    if (lane < nb) sidx[lane] = vedg[base + lane];
    __syncthreads();
    for (int j = 0; j < nb; ++j) {
      if (lane < C) a0 += Xe[(size_t)sidx[j] * ldXe + lane];
    }
  }
  a0 *= dv;
  float val = (lane < C) ? a0 : -3.4e38f;
  float m = val;
#pragma unroll
  for (int o = 32; o > 0; o >>= 1) m = fmaxf(m, __shfl_xor(m, o));
  float ex = (lane < C) ? expf(val - m) : 0.f;
  float s = ex;
#pragma unroll
  for (int o = 32; o > 0; o >>= 1) s += __shfl_xor(s, o);
  float ls = logf(s);
  if (lane < C) out[(size_t)v * C + lane] = val - m - ls;
}

extern "C" void kernel_launch(void* const* d_in, const int* in_sizes, int n_in,
                              void* d_out, int out_size, void* d_ws, size_t ws_size,
                              hipStream_t stream) {
  (void)in_sizes; (void)n_in; (void)out_size; (void)ws_size;
  const float* X = (const float*)d_in[0];
  const int* vertex = (const int*)d_in[1];
  const int* edges = (const int*)d_in[2];
  const float* W1 = (const float*)d_in[3];
  const float* W2 = (const float*)d_in[4];
  const float* Wout = (const float*)d_in[5];
  const float* degE = (const float*)d_in[6];
  const float* degV = (const float*)d_in[7];
  float* out = (float*)d_out;

  char* ws = (char*)d_ws;
  size_t off = 0;
  auto alloc = [&](size_t bytes) -> void* {
    void* p = ws + off;
    off += (bytes + 255) & ~(size_t)255;
    return p;
  };
  bf16* Xb  = (bf16*)alloc((size_t)N_NODES * 512 * sizeof(bf16));   // GEMM A / layer input
  bf16* Yb  = (bf16*)alloc((size_t)N_NODES * 512 * sizeof(bf16));   // GEMM out (layers 1,2)
  bf16* XeB = (bf16*)alloc((size_t)N_EDGES_C * 512 * sizeof(bf16)); // edge feats (layers 1,2)
  float* Y40  = (float*)alloc((size_t)N_NODES * 64 * sizeof(float));   // layer-3 GEMM out
  float* Xe40 = (float*)alloc((size_t)N_EDGES_C * 64 * sizeof(float)); // layer-3 edge feats
  bf16* Wt  = (bf16*)alloc((size_t)512 * 512 * sizeof(bf16));
  int* eoff = (int*)alloc((N_EDGES_C + 1) * sizeof(int));
  int* voff = (int*)alloc((N_NODES + 1) * sizeof(int));
  int* evtx = (int*)alloc((size_t)NNZ_C * sizeof(int));
  int* vedg = (int*)alloc((size_t)NNZ_C * sizeof(int));
  int* cntE = (int*)alloc(N_EDGES_C * sizeof(int));
  int* cntV = (int*)alloc(N_NODES * sizeof(int));
  int* curE = (int*)alloc(N_EDGES_C * sizeof(int));
  int* curV = (int*)alloc(N_NODES * sizeof(int));

  hipMemsetAsync(cntE, 0, N_EDGES_C * sizeof(int), stream);
  hipMemsetAsync(cntV, 0, N_NODES * sizeof(int), stream);
  hipMemsetAsync(curE, 0, N_EDGES_C * sizeof(int), stream);
  hipMemsetAsync(curV, 0, N_NODES * sizeof(int), stream);

  hist_kernel<<<(NNZ_C + 255) / 256, 256, 0, stream>>>(vertex, edges, cntV, cntE, NNZ_C);
  exscan_kernel<<<1, 1024, 0, stream>>>(cntE, eoff, N_EDGES_C);
  exscan_kernel<<<1, 1024, 0, stream>>>(cntV, voff, N_NODES);
  scatter_kernel<<<(NNZ_C + 255) / 256, 256, 0, stream>>>(vertex, edges, eoff, voff,
                                                          curE, curV, evtx, vedg, NNZ_C);

  convert_f2b<<<(N_NODES * 512 / 4 + 255) / 256, 256, 0, stream>>>(X, Xb, (size_t)N_NODES * 512);

  const int MB = (N_NODES + 127) / 128;

  // ---- layer 1 ----
  transpose_w<<<(512 * 512 + 255) / 256, 256, 0, stream>>>(W1, Wt, 512, 512, 512);
  {
    dim3 g(MB, 4);
    gemm_bf16_kernel<1><<<g, 256, 0, stream>>>(Xb, Wt, nullptr, Yb, N_NODES, 512, 512, 512);
  }
  edge_agg_bf16<<<N_EDGES_C, 256, 0, stream>>>(Yb, eoff, evtx, degE, XeB);
  vtx_agg_bf16<<<N_NODES, 256, 0, stream>>>(XeB, voff, vedg, degV, Xb);

  // ---- layer 2 ----
  transpose_w<<<(512 * 512 + 255) / 256, 256, 0, stream>>>(W2, Wt, 512, 512, 512);
  {
    dim3 g(MB, 4);
    gemm_bf16_kernel<1><<<g, 256, 0, stream>>>(Xb, Wt, nullptr, Yb, N_NODES, 512, 512, 512);
  }
  edge_agg_bf16<<<N_EDGES_C, 256, 0, stream>>>(Yb, eoff, evtx, degE, XeB);
  vtx_agg_bf16<<<N_NODES, 256, 0, stream>>>(XeB, voff, vedg, degV, Xb);

  // ---- layer 3 (C=40) ----
  transpose_w<<<(128 * 512 + 255) / 256, 256, 0, stream>>>(Wout, Wt, 512, 40, 128);
  {
    dim3 g(MB, 1);
    gemm_bf16_kernel<0><<<g, 256, 0, stream>>>(Xb, Wt, Y40, nullptr, N_NODES, 512, 40, 40);
  }
  edge_agg_f32<<<N_EDGES_C, 64, 0, stream>>>(Y40, 40, eoff, evtx, degE, Xe40, 40, 40);
  vtx_agg_lsm<<<N_NODES, 64, 0, stream>>>(Xe40, 40, voff, vedg, degV, out, 40);
}

// Round 4
// 655.113 us; speedup vs baseline: 2.0042x; 1.0810x over previous
//
#include <hip/hip_runtime.h>

#define N_NODES 50000
#define N_EDGES_C 25000
#define NNZ_C 400000

typedef __bf16 bf16;
typedef __bf16 bf16x8 __attribute__((ext_vector_type(8)));
typedef __bf16 bf16x4 __attribute__((ext_vector_type(4)));
typedef __bf16 bf16x2 __attribute__((ext_vector_type(2)));
typedef float f32x4 __attribute__((ext_vector_type(4)));

typedef __attribute__((address_space(1))) const void as1_cvoid;
typedef __attribute__((address_space(3))) void as3_void;

__device__ __forceinline__ void gload_lds16(const bf16* g, bf16* l) {
  __builtin_amdgcn_global_load_lds((as1_cvoid*)g, (as3_void*)l, 16, 0, 0);
}

// ---------------- CSR build ----------------
__global__ void hist_kernel(const int* __restrict__ vtx, const int* __restrict__ edg,
                            int* __restrict__ cntV, int* __restrict__ cntE, int nnz) {
  int i = blockIdx.x * blockDim.x + threadIdx.x;
  if (i < nnz) {
    atomicAdd(&cntV[vtx[i]], 1);
    atomicAdd(&cntE[edg[i]], 1);
  }
}

__global__ void exscan_kernel(const int* __restrict__ cnt, int* __restrict__ off, int n) {
  __shared__ int part[1024];
  const int t = threadIdx.x;
  const int per = (n + 1023) / 1024;
  const int beg = t * per;
  const int end = min(beg + per, n);
  int s = 0;
  for (int i = beg; i < end; ++i) s += cnt[i];
  part[t] = s;
  __syncthreads();
  for (int d = 1; d < 1024; d <<= 1) {
    int x = (t >= d) ? part[t - d] : 0;
    __syncthreads();
    part[t] += x;
    __syncthreads();
  }
  int run = (t > 0) ? part[t - 1] : 0;
  for (int i = beg; i < end; ++i) { off[i] = run; run += cnt[i]; }
  if (t == 1023) off[n] = part[1023];
}

__global__ void scatter_kernel(const int* __restrict__ vtx, const int* __restrict__ edg,
                               const int* __restrict__ eoff, const int* __restrict__ voff,
                               int* __restrict__ curE, int* __restrict__ curV,
                               int* __restrict__ evtx, int* __restrict__ vedg, int nnz) {
  int i = blockIdx.x * blockDim.x + threadIdx.x;
  if (i < nnz) {
    int e = edg[i], v = vtx[i];
    int p = atomicAdd(&curE[e], 1);
    evtx[eoff[e] + p] = v;
    int q = atomicAdd(&curV[v], 1);
    vedg[voff[v] + q] = e;
  }
}

// ---------------- conversions ----------------
__global__ void convert_f2b(const float* __restrict__ in, bf16* __restrict__ out, size_t n) {
  size_t i = ((size_t)blockIdx.x * blockDim.x + threadIdx.x) * 4;
  if (i >= n) return;
  float4 v = *(const float4*)(in + i);
  bf16x4 o;
  o[0] = (bf16)v.x; o[1] = (bf16)v.y; o[2] = (bf16)v.z; o[3] = (bf16)v.w;
  *(bf16x4*)(out + i) = o;
}

// Wt[n][k] = (n < N) ? W[k][n] : 0, one thread per output element
__global__ void transpose_w(const float* __restrict__ W, bf16* __restrict__ Wt,
                            int K, int N, int NtRows) {
  int idx = blockIdx.x * blockDim.x + threadIdx.x;
  int total = NtRows * K;
  if (idx >= total) return;
  int n = idx / K;
  int k = idx - n * K;
  Wt[idx] = (n < N) ? (bf16)W[(size_t)k * N + n] : (bf16)0.0f;
}

// ---------------- GEMM: C[M][*] = A[M][K](bf16) @ B[n][K](bf16, row n = col n) ----------------
// LDS layout MUST be linear [128][32] (no pad): global_load_lds writes
// wave-uniform base + lane*16.  OOB A-rows load garbage but MFMA row r of D
// depends only on row r of A, and rows >= M are never stored.
template <int BF16OUT>
__global__ __launch_bounds__(256) void gemm_bf16_kernel(
    const bf16* __restrict__ A, const bf16* __restrict__ B,
    float* __restrict__ Cf, bf16* __restrict__ Cb, int M, int K, int ldC, int Nstore) {
  __shared__ bf16 Al[128][32];
  __shared__ bf16 Bl[128][32];
  const int t = threadIdx.x;
  const int m0 = blockIdx.x * 128;
  const int n0 = blockIdx.y * 128;
  const int w = t >> 6, lane = t & 63;
  const int wr = w >> 1, wc = w & 1;
  const int lr = lane & 15, lk = (lane >> 4) << 3;

  f32x4 acc[4][4];
#pragma unroll
  for (int m = 0; m < 4; ++m)
#pragma unroll
    for (int n = 0; n < 4; ++n) acc[m][n] = (f32x4){0.f, 0.f, 0.f, 0.f};

  // staging address: wave w covers 16 rows (w*16 + lane>>2), lane&3 gives 16B chunk
  const int srow = w * 16 + (lane >> 2);
  const int scol = (lane & 3) << 3;  // element offset

  for (int kk = 0; kk < K; kk += 32) {
#pragma unroll
    for (int p = 0; p < 2; ++p) {
      const bf16* gA = A + (size_t)(m0 + p * 64 + srow) * K + kk + scol;
      gload_lds16(gA, &Al[p * 64 + w * 16][0]);
      const bf16* gB = B + (size_t)(n0 + p * 64 + srow) * K + kk + scol;
      gload_lds16(gB, &Bl[p * 64 + w * 16][0]);
    }
    __syncthreads();
    bf16x8 af[4], bfr[4];
#pragma unroll
    for (int m = 0; m < 4; ++m) af[m] = *(const bf16x8*)(&Al[wr * 64 + m * 16 + lr][lk]);
#pragma unroll
    for (int n = 0; n < 4; ++n) bfr[n] = *(const bf16x8*)(&Bl[wc * 64 + n * 16 + lr][lk]);
#pragma unroll
    for (int m = 0; m < 4; ++m)
#pragma unroll
      for (int n = 0; n < 4; ++n)
        acc[m][n] = __builtin_amdgcn_mfma_f32_16x16x32_bf16(af[m], bfr[n], acc[m][n], 0, 0, 0);
    __syncthreads();
  }

  const int cr = (lane >> 4) << 2;  // C/D: col = lane&15, row = (lane>>4)*4 + i
  const int cc = lane & 15;
#pragma unroll
  for (int m = 0; m < 4; ++m) {
#pragma unroll
    for (int n = 0; n < 4; ++n) {
      int gc = n0 + wc * 64 + n * 16 + cc;
      if (gc >= Nstore) continue;
#pragma unroll
      for (int i = 0; i < 4; ++i) {
        int gr = m0 + wr * 64 + m * 16 + cr + i;
        if (gr < M) {
          if (BF16OUT) Cb[(size_t)gr * ldC + gc] = (bf16)acc[m][n][i];
          else         Cf[(size_t)gr * ldC + gc] = acc[m][n][i];
        }
      }
    }
  }
}

// ---------------- wave-per-edge aggregation (bf16 in/out, C=512) ----------------
// one 64-lane wave per edge; lane loads bf16x8 (16B) -> 1KB row per load inst
__global__ __launch_bounds__(256) void edge_agg_w(
    const bf16* __restrict__ Y, const int* __restrict__ eoff, const int* __restrict__ evtx,
    const float* __restrict__ degE, bf16* __restrict__ Xe, int nE) {
  const int wv = (blockIdx.x * 256 + threadIdx.x) >> 6;
  if (wv >= nE) return;
  const int lane = threadIdx.x & 63;
  const int beg = eoff[wv], end = eoff[wv + 1];
  const int cnt = end - beg;
  const float scale = (cnt > 0) ? degE[wv] / (float)cnt : 0.f;
  float acc[8] = {0.f, 0.f, 0.f, 0.f, 0.f, 0.f, 0.f, 0.f};
  for (int base = beg; base < end; base += 64) {
    const int nb = min(64, end - base);
    int myidx = (lane < nb) ? evtx[base + lane] : 0;
    int j = 0;
    for (; j + 1 < nb; j += 2) {
      const int i0 = __shfl(myidx, j);
      const int i1 = __shfl(myidx, j + 1);
      bf16x8 v0 = *(const bf16x8*)(Y + (size_t)i0 * 512 + lane * 8);
      bf16x8 v1 = *(const bf16x8*)(Y + (size_t)i1 * 512 + lane * 8);
#pragma unroll
      for (int q = 0; q < 8; ++q) acc[q] += (float)v0[q] + (float)v1[q];
    }
    if (j < nb) {
      const int i0 = __shfl(myidx, j);
      bf16x8 v0 = *(const bf16x8*)(Y + (size_t)i0 * 512 + lane * 8);
#pragma unroll
      for (int q = 0; q < 8; ++q) acc[q] += (float)v0[q];
    }
  }
  bf16x8 o;
#pragma unroll
  for (int q = 0; q < 8; ++q) o[q] = (bf16)(acc[q] * scale);
  *(bf16x8*)(Xe + (size_t)wv * 512 + lane * 8) = o;
}

// ---------------- wave-per-vertex aggregation (bf16 in/out, relu, C=512) ----------------
__global__ __launch_bounds__(256) void vtx_agg_w(
    const bf16* __restrict__ Xe, const int* __restrict__ voff, const int* __restrict__ vedg,
    const float* __restrict__ degV, bf16* __restrict__ outB, int nV) {
  const int wv = (blockIdx.x * 256 + threadIdx.x) >> 6;
  if (wv >= nV) return;
  const int lane = threadIdx.x & 63;
  const int beg = voff[wv], end = voff[wv + 1];
  const float dv = degV[wv];
  float acc[8] = {0.f, 0.f, 0.f, 0.f, 0.f, 0.f, 0.f, 0.f};
  for (int base = beg; base < end; base += 64) {
    const int nb = min(64, end - base);
    int myidx = (lane < nb) ? vedg[base + lane] : 0;
    int j = 0;
    for (; j + 1 < nb; j += 2) {
      const int i0 = __shfl(myidx, j);
      const int i1 = __shfl(myidx, j + 1);
      bf16x8 v0 = *(const bf16x8*)(Xe + (size_t)i0 * 512 + lane * 8);
      bf16x8 v1 = *(const bf16x8*)(Xe + (size_t)i1 * 512 + lane * 8);
#pragma unroll
      for (int q = 0; q < 8; ++q) acc[q] += (float)v0[q] + (float)v1[q];
    }
    if (j < nb) {
      const int i0 = __shfl(myidx, j);
      bf16x8 v0 = *(const bf16x8*)(Xe + (size_t)i0 * 512 + lane * 8);
#pragma unroll
      for (int q = 0; q < 8; ++q) acc[q] += (float)v0[q];
    }
  }
  bf16x8 o;
#pragma unroll
  for (int q = 0; q < 8; ++q) o[q] = (bf16)fmaxf(acc[q] * dv, 0.f);
  *(bf16x8*)(outB + (size_t)wv * 512 + lane * 8) = o;
}

// ---------------- edge aggregation f32 (layer 3, C=40, block=64) ----------------
__global__ void edge_agg_f32(const float* __restrict__ Y, int ldY,
                             const int* __restrict__ eoff, const int* __restrict__ evtx,
                             const float* __restrict__ degE,
                             float* __restrict__ Xe, int ldXe, int C) {
  const int e = blockIdx.x;
  const int beg = eoff[e], end = eoff[e + 1];
  const int cnt = end - beg;
  const float scale = (cnt > 0) ? degE[e] / (float)cnt : 0.f;
  const int c0 = threadIdx.x;
  float a0 = 0.f;
  __shared__ int sidx[64];
  for (int base = beg; base < end; base += blockDim.x) {
    const int nb = min((int)blockDim.x, end - base);
    __syncthreads();
    if ((int)threadIdx.x < nb) sidx[threadIdx.x] = evtx[base + threadIdx.x];
    __syncthreads();
    for (int j = 0; j < nb; ++j) {
      if (c0 < C) a0 += Y[(size_t)sidx[j] * ldY + c0];
    }
  }
  if (c0 < C) Xe[(size_t)e * ldXe + c0] = a0 * scale;
}

// ---------------- final vertex aggregation + log_softmax fused (C=40, 1 wave) ----------------
__global__ void vtx_agg_lsm(const float* __restrict__ Xe, int ldXe,
                            const int* __restrict__ voff, const int* __restrict__ vedg,
                            const float* __restrict__ degV,
                            float* __restrict__ out, int C) {
  const int v = blockIdx.x;
  const int beg = voff[v], end = voff[v + 1];
  const float dv = degV[v];
  const int lane = threadIdx.x;  // 64 = one wave
  float a0 = 0.f;
  __shared__ int sidx[64];
  for (int base = beg; base < end; base += 64) {
    const int nb = min(64, end - base);
    __syncthreads();
    if (lane < nb) sidx[lane] = vedg[base + lane];
    __syncthreads();
    for (int j = 0; j < nb; ++j) {
      if (lane < C) a0 += Xe[(size_t)sidx[j] * ldXe + lane];
    }
  }
  a0 *= dv;
  float val = (lane < C) ? a0 : -3.4e38f;
  float m = val;
#pragma unroll
  for (int o = 32; o > 0; o >>= 1) m = fmaxf(m, __shfl_xor(m, o));
  float ex = (lane < C) ? expf(val - m) : 0.f;
  float s = ex;
#pragma unroll
  for (int o = 32; o > 0; o >>= 1) s += __shfl_xor(s, o);
  float ls = logf(s);
  if (lane < C) out[(size_t)v * C + lane] = val - m - ls;
}

extern "C" void kernel_launch(void* const* d_in, const int* in_sizes, int n_in,
                              void* d_out, int out_size, void* d_ws, size_t ws_size,
                              hipStream_t stream) {
  (void)in_sizes; (void)n_in; (void)out_size; (void)ws_size;
  const float* X = (const float*)d_in[0];
  const int* vertex = (const int*)d_in[1];
  const int* edges = (const int*)d_in[2];
  const float* W1 = (const float*)d_in[3];
  const float* W2 = (const float*)d_in[4];
  const float* Wout = (const float*)d_in[5];
  const float* degE = (const float*)d_in[6];
  const float* degV = (const float*)d_in[7];
  float* out = (float*)d_out;

  char* ws = (char*)d_ws;
  size_t off = 0;
  auto alloc = [&](size_t bytes) -> void* {
    void* p = ws + off;
    off += (bytes + 255) & ~(size_t)255;
    return p;
  };
  bf16* Xb  = (bf16*)alloc((size_t)N_NODES * 512 * sizeof(bf16));   // GEMM A / layer input
  bf16* Yb  = (bf16*)alloc((size_t)N_NODES * 512 * sizeof(bf16));   // GEMM out (layers 1,2)
  bf16* XeB = (bf16*)alloc((size_t)N_EDGES_C * 512 * sizeof(bf16)); // edge feats (layers 1,2)
  float* Y40  = (float*)alloc((size_t)N_NODES * 64 * sizeof(float));   // layer-3 GEMM out
  float* Xe40 = (float*)alloc((size_t)N_EDGES_C * 64 * sizeof(float)); // layer-3 edge feats
  bf16* Wt  = (bf16*)alloc((size_t)512 * 512 * sizeof(bf16));
  int* eoff = (int*)alloc((N_EDGES_C + 1) * sizeof(int));
  int* voff = (int*)alloc((N_NODES + 1) * sizeof(int));
  int* evtx = (int*)alloc((size_t)NNZ_C * sizeof(int));
  int* vedg = (int*)alloc((size_t)NNZ_C * sizeof(int));
  int* cntE = (int*)alloc(N_EDGES_C * sizeof(int));
  int* cntV = (int*)alloc(N_NODES * sizeof(int));
  int* curE = (int*)alloc(N_EDGES_C * sizeof(int));
  int* curV = (int*)alloc(N_NODES * sizeof(int));

  hipMemsetAsync(cntE, 0, N_EDGES_C * sizeof(int), stream);
  hipMemsetAsync(cntV, 0, N_NODES * sizeof(int), stream);
  hipMemsetAsync(curE, 0, N_EDGES_C * sizeof(int), stream);
  hipMemsetAsync(curV, 0, N_NODES * sizeof(int), stream);

  hist_kernel<<<(NNZ_C + 255) / 256, 256, 0, stream>>>(vertex, edges, cntV, cntE, NNZ_C);
  exscan_kernel<<<1, 1024, 0, stream>>>(cntE, eoff, N_EDGES_C);
  exscan_kernel<<<1, 1024, 0, stream>>>(cntV, voff, N_NODES);
  scatter_kernel<<<(NNZ_C + 255) / 256, 256, 0, stream>>>(vertex, edges, eoff, voff,
                                                          curE, curV, evtx, vedg, NNZ_C);

  convert_f2b<<<(N_NODES * 512 / 4 + 255) / 256, 256, 0, stream>>>(X, Xb, (size_t)N_NODES * 512);

  const int MB = (N_NODES + 127) / 128;

  // ---- layer 1 ----
  transpose_w<<<(512 * 512 + 255) / 256, 256, 0, stream>>>(W1, Wt, 512, 512, 512);
  {
    dim3 g(MB, 4);
    gemm_bf16_kernel<1><<<g, 256, 0, stream>>>(Xb, Wt, nullptr, Yb, N_NODES, 512, 512, 512);
  }
  edge_agg_w<<<(N_EDGES_C + 3) / 4, 256, 0, stream>>>(Yb, eoff, evtx, degE, XeB, N_EDGES_C);
  vtx_agg_w<<<(N_NODES + 3) / 4, 256, 0, stream>>>(XeB, voff, vedg, degV, Xb, N_NODES);

  // ---- layer 2 ----
  transpose_w<<<(512 * 512 + 255) / 256, 256, 0, stream>>>(W2, Wt, 512, 512, 512);
  {
    dim3 g(MB, 4);
    gemm_bf16_kernel<1><<<g, 256, 0, stream>>>(Xb, Wt, nullptr, Yb, N_NODES, 512, 512, 512);
  }
  edge_agg_w<<<(N_EDGES_C + 3) / 4, 256, 0, stream>>>(Yb, eoff, evtx, degE, XeB, N_EDGES_C);
  vtx_agg_w<<<(N_NODES + 3) / 4, 256, 0, stream>>>(XeB, voff, vedg, degV, Xb, N_NODES);

  // ---- layer 3 (C=40) ----
  transpose_w<<<(128 * 512 + 255) / 256, 256, 0, stream>>>(Wout, Wt, 512, 40, 128);
  {
    dim3 g(MB, 1);
    gemm_bf16_kernel<0><<<g, 256, 0, stream>>>(Xb, Wt, Y40, nullptr, N_NODES, 512, 40, 40);
  }
  edge_agg_f32<<<N_EDGES_C, 64, 0, stream>>>(Y40, 40, eoff, evtx, degE, Xe40, 40, 40);
  vtx_agg_lsm<<<N_NODES, 64, 0, stream>>>(Xe40, 40, voff, vedg, degV, out, 40);
}

// Round 5
// 566.329 us; speedup vs baseline: 2.3185x; 1.1568x over previous
//
#include <hip/hip_runtime.h>

#define N_NODES 50000
#define N_EDGES_C 25000
#define NNZ_C 400000
#define SCHUNK 2048  // elements per scan block (256 threads x 8)

typedef __bf16 bf16;
typedef __bf16 bf16x8 __attribute__((ext_vector_type(8)));
typedef __bf16 bf16x4 __attribute__((ext_vector_type(4)));
typedef __bf16 bf16x2 __attribute__((ext_vector_type(2)));
typedef float f32x4 __attribute__((ext_vector_type(4)));

typedef __attribute__((address_space(1))) const void as1_cvoid;
typedef __attribute__((address_space(3))) void as3_void;

__device__ __forceinline__ void gload_lds16(const bf16* g, bf16* l) {
  __builtin_amdgcn_global_load_lds((as1_cvoid*)g, (as3_void*)l, 16, 0, 0);
}

// ---------------- CSR build ----------------
__global__ void hist_kernel(const int* __restrict__ vtx, const int* __restrict__ edg,
                            int* __restrict__ cntV, int* __restrict__ cntE, int nnz) {
  int i = blockIdx.x * blockDim.x + threadIdx.x;
  if (i < nnz) {
    atomicAdd(&cntV[vtx[i]], 1);
    atomicAdd(&cntE[edg[i]], 1);
  }
}

// phase 1: per-block partial sums over SCHUNK-chunks
__global__ void scan_part(const int* __restrict__ cnt, int* __restrict__ part, int n) {
  __shared__ int red[256];
  const int b = blockIdx.x, t = threadIdx.x;
  const int base = b * SCHUNK + t * 8;
  int s = 0;
#pragma unroll
  for (int q = 0; q < 8; ++q) {
    int i = base + q;
    if (i < n) s += cnt[i];
  }
  red[t] = s;
  __syncthreads();
  for (int d = 128; d > 0; d >>= 1) {
    if (t < d) red[t] += red[t + d];
    __syncthreads();
  }
  if (t == 0) part[b] = red[0];
}

// phase 2: one wave exclusive-scans the partials (nparts <= 64), writes off[n]=total
__global__ void scan_mid(int* __restrict__ part, int* __restrict__ off, int nparts, int n) {
  const int lane = threadIdx.x;  // 64 threads
  int orig = (lane < nparts) ? part[lane] : 0;
  int v = orig;
  for (int o = 1; o < 64; o <<= 1) {
    int x = __shfl_up(v, o);
    if (lane >= o) v += x;
  }
  if (lane < nparts) part[lane] = v - orig;  // exclusive
  if (lane == 63) off[n] = v;                // grand total
}

// phase 3: per-block exclusive scan with global offset
__global__ void scan_final(const int* __restrict__ cnt, const int* __restrict__ part,
                           int* __restrict__ off, int n) {
  __shared__ int tsum[256];
  const int b = blockIdx.x, t = threadIdx.x;
  const int base = b * SCHUNK + t * 8;
  int loc[8];
  int s = 0;
#pragma unroll
  for (int q = 0; q < 8; ++q) {
    int i = base + q;
    loc[q] = (i < n) ? cnt[i] : 0;
    s += loc[q];
  }
  tsum[t] = s;
  __syncthreads();
  for (int d = 1; d < 256; d <<= 1) {
    int x = (t >= d) ? tsum[t - d] : 0;
    __syncthreads();
    tsum[t] += x;
    __syncthreads();
  }
  int run = part[b] + ((t > 0) ? tsum[t - 1] : 0);
#pragma unroll
  for (int q = 0; q < 8; ++q) {
    int i = base + q;
    if (i < n) off[i] = run;
    run += loc[q];
  }
}

__global__ void scatter_kernel(const int* __restrict__ vtx, const int* __restrict__ edg,
                               const int* __restrict__ eoff, const int* __restrict__ voff,
                               int* __restrict__ curE, int* __restrict__ curV,
                               int* __restrict__ evtx, int* __restrict__ vedg, int nnz) {
  int i = blockIdx.x * blockDim.x + threadIdx.x;
  if (i < nnz) {
    int e = edg[i], v = vtx[i];
    int p = atomicAdd(&curE[e], 1);
    evtx[eoff[e] + p] = v;
    int q = atomicAdd(&curV[v], 1);
    vedg[voff[v] + q] = e;
  }
}

// ---------------- conversions ----------------
__global__ void convert_f2b(const float* __restrict__ in, bf16* __restrict__ out, size_t n) {
  size_t i = ((size_t)blockIdx.x * blockDim.x + threadIdx.x) * 4;
  if (i >= n) return;
  float4 v = *(const float4*)(in + i);
  bf16x4 o;
  o[0] = (bf16)v.x; o[1] = (bf16)v.y; o[2] = (bf16)v.z; o[3] = (bf16)v.w;
  *(bf16x4*)(out + i) = o;
}

// Wt[n][k] = (n < N) ? W[k][n] : 0, one thread per output element
__global__ void transpose_w(const float* __restrict__ W, bf16* __restrict__ Wt,
                            int K, int N, int NtRows) {
  int idx = blockIdx.x * blockDim.x + threadIdx.x;
  int total = NtRows * K;
  if (idx >= total) return;
  int n = idx / K;
  int k = idx - n * K;
  Wt[idx] = (n < N) ? (bf16)W[(size_t)k * N + n] : (bf16)0.0f;
}

// ---------------- GEMM: C[M][*] = A[M][K](bf16) @ B[n][K](bf16, row n = col n) ----------------
template <int BF16OUT>
__global__ __launch_bounds__(256) void gemm_bf16_kernel(
    const bf16* __restrict__ A, const bf16* __restrict__ B,
    float* __restrict__ Cf, bf16* __restrict__ Cb, int M, int K, int ldC, int Nstore) {
  __shared__ bf16 Al[128][32];
  __shared__ bf16 Bl[128][32];
  const int t = threadIdx.x;
  const int m0 = blockIdx.x * 128;
  const int n0 = blockIdx.y * 128;
  const int w = t >> 6, lane = t & 63;
  const int wr = w >> 1, wc = w & 1;
  const int lr = lane & 15, lk = (lane >> 4) << 3;

  f32x4 acc[4][4];
#pragma unroll
  for (int m = 0; m < 4; ++m)
#pragma unroll
    for (int n = 0; n < 4; ++n) acc[m][n] = (f32x4){0.f, 0.f, 0.f, 0.f};

  const int srow = w * 16 + (lane >> 2);
  const int scol = (lane & 3) << 3;

  for (int kk = 0; kk < K; kk += 32) {
#pragma unroll
    for (int p = 0; p < 2; ++p) {
      const bf16* gA = A + (size_t)(m0 + p * 64 + srow) * K + kk + scol;
      gload_lds16(gA, &Al[p * 64 + w * 16][0]);
      const bf16* gB = B + (size_t)(n0 + p * 64 + srow) * K + kk + scol;
      gload_lds16(gB, &Bl[p * 64 + w * 16][0]);
    }
    __syncthreads();
    bf16x8 af[4], bfr[4];
#pragma unroll
    for (int m = 0; m < 4; ++m) af[m] = *(const bf16x8*)(&Al[wr * 64 + m * 16 + lr][lk]);
#pragma unroll
    for (int n = 0; n < 4; ++n) bfr[n] = *(const bf16x8*)(&Bl[wc * 64 + n * 16 + lr][lk]);
#pragma unroll
    for (int m = 0; m < 4; ++m)
#pragma unroll
      for (int n = 0; n < 4; ++n)
        acc[m][n] = __builtin_amdgcn_mfma_f32_16x16x32_bf16(af[m], bfr[n], acc[m][n], 0, 0, 0);
    __syncthreads();
  }

  const int cr = (lane >> 4) << 2;
  const int cc = lane & 15;
#pragma unroll
  for (int m = 0; m < 4; ++m) {
#pragma unroll
    for (int n = 0; n < 4; ++n) {
      int gc = n0 + wc * 64 + n * 16 + cc;
      if (gc >= Nstore) continue;
#pragma unroll
      for (int i = 0; i < 4; ++i) {
        int gr = m0 + wr * 64 + m * 16 + cr + i;
        if (gr < M) {
          if (BF16OUT) Cb[(size_t)gr * ldC + gc] = (bf16)acc[m][n][i];
          else         Cf[(size_t)gr * ldC + gc] = acc[m][n][i];
        }
      }
    }
  }
}

// ---------------- wave-per-edge aggregation (bf16 in/out, C=512) ----------------
__global__ __launch_bounds__(256) void edge_agg_w(
    const bf16* __restrict__ Y, const int* __restrict__ eoff, const int* __restrict__ evtx,
    const float* __restrict__ degE, bf16* __restrict__ Xe, int nE) {
  const int wv = (blockIdx.x * 256 + threadIdx.x) >> 6;
  if (wv >= nE) return;
  const int lane = threadIdx.x & 63;
  const int beg = eoff[wv], end = eoff[wv + 1];
  const int cnt = end - beg;
  const float scale = (cnt > 0) ? degE[wv] / (float)cnt : 0.f;
  float acc[8] = {0.f, 0.f, 0.f, 0.f, 0.f, 0.f, 0.f, 0.f};
  for (int base = beg; base < end; base += 64) {
    const int nb = min(64, end - base);
    int myidx = (lane < nb) ? evtx[base + lane] : 0;
    int j = 0;
    for (; j + 1 < nb; j += 2) {
      const int i0 = __shfl(myidx, j);
      const int i1 = __shfl(myidx, j + 1);
      bf16x8 v0 = *(const bf16x8*)(Y + (size_t)i0 * 512 + lane * 8);
      bf16x8 v1 = *(const bf16x8*)(Y + (size_t)i1 * 512 + lane * 8);
#pragma unroll
      for (int q = 0; q < 8; ++q) acc[q] += (float)v0[q] + (float)v1[q];
    }
    if (j < nb) {
      const int i0 = __shfl(myidx, j);
      bf16x8 v0 = *(const bf16x8*)(Y + (size_t)i0 * 512 + lane * 8);
#pragma unroll
      for (int q = 0; q < 8; ++q) acc[q] += (float)v0[q];
    }
  }
  bf16x8 o;
#pragma unroll
  for (int q = 0; q < 8; ++q) o[q] = (bf16)(acc[q] * scale);
  *(bf16x8*)(Xe + (size_t)wv * 512 + lane * 8) = o;
}

// ---------------- wave-per-vertex aggregation (bf16 in/out, relu, C=512) ----------------
__global__ __launch_bounds__(256) void vtx_agg_w(
    const bf16* __restrict__ Xe, const int* __restrict__ voff, const int* __restrict__ vedg,
    const float* __restrict__ degV, bf16* __restrict__ outB, int nV) {
  const int wv = (blockIdx.x * 256 + threadIdx.x) >> 6;
  if (wv >= nV) return;
  const int lane = threadIdx.x & 63;
  const int beg = voff[wv], end = voff[wv + 1];
  const float dv = degV[wv];
  float acc[8] = {0.f, 0.f, 0.f, 0.f, 0.f, 0.f, 0.f, 0.f};
  for (int base = beg; base < end; base += 64) {
    const int nb = min(64, end - base);
    int myidx = (lane < nb) ? vedg[base + lane] : 0;
    int j = 0;
    for (; j + 1 < nb; j += 2) {
      const int i0 = __shfl(myidx, j);
      const int i1 = __shfl(myidx, j + 1);
      bf16x8 v0 = *(const bf16x8*)(Xe + (size_t)i0 * 512 + lane * 8);
      bf16x8 v1 = *(const bf16x8*)(Xe + (size_t)i1 * 512 + lane * 8);
#pragma unroll
      for (int q = 0; q < 8; ++q) acc[q] += (float)v0[q] + (float)v1[q];
    }
    if (j < nb) {
      const int i0 = __shfl(myidx, j);
      bf16x8 v0 = *(const bf16x8*)(Xe + (size_t)i0 * 512 + lane * 8);
#pragma unroll
      for (int q = 0; q < 8; ++q) acc[q] += (float)v0[q];
    }
  }
  bf16x8 o;
#pragma unroll
  for (int q = 0; q < 8; ++q) o[q] = (bf16)fmaxf(acc[q] * dv, 0.f);
  *(bf16x8*)(outB + (size_t)wv * 512 + lane * 8) = o;
}

// ---------------- edge aggregation f32 (layer 3, C=40, block=64) ----------------
__global__ void edge_agg_f32(const float* __restrict__ Y, int ldY,
                             const int* __restrict__ eoff, const int* __restrict__ evtx,
                             const float* __restrict__ degE,
                             float* __restrict__ Xe, int ldXe, int C) {
  const int e = blockIdx.x;
  const int beg = eoff[e], end = eoff[e + 1];
  const int cnt = end - beg;
  const float scale = (cnt > 0) ? degE[e] / (float)cnt : 0.f;
  const int c0 = threadIdx.x;
  float a0 = 0.f;
  __shared__ int sidx[64];
  for (int base = beg; base < end; base += blockDim.x) {
    const int nb = min((int)blockDim.x, end - base);
    __syncthreads();
    if ((int)threadIdx.x < nb) sidx[threadIdx.x] = evtx[base + threadIdx.x];
    __syncthreads();
    for (int j = 0; j < nb; ++j) {
      if (c0 < C) a0 += Y[(size_t)sidx[j] * ldY + c0];
    }
  }
  if (c0 < C) Xe[(size_t)e * ldXe + c0] = a0 * scale;
}

// ---------------- final vertex aggregation + log_softmax fused (C=40, 1 wave) ----------------
__global__ void vtx_agg_lsm(const float* __restrict__ Xe, int ldXe,
                            const int* __restrict__ voff, const int* __restrict__ vedg,
                            const float* __restrict__ degV,
                            float* __restrict__ out, int C) {
  const int v = blockIdx.x;
  const int beg = voff[v], end = voff[v + 1];
  const float dv = degV[v];
  const int lane = threadIdx.x;
  float a0 = 0.f;
  __shared__ int sidx[64];
  for (int base = beg; base < end; base += 64) {
    const int nb = min(64, end - base);
    __syncthreads();
    if (lane < nb) sidx[lane] = vedg[base + lane];
    __syncthreads();
    for (int j = 0; j < nb; ++j) {
      if (lane < C) a0 += Xe[(size_t)sidx[j] * ldXe + lane];
    }
  }
  a0 *= dv;
  float val = (lane < C) ? a0 : -3.4e38f;
  float m = val;
#pragma unroll
  for (int o = 32; o > 0; o >>= 1) m = fmaxf(m, __shfl_xor(m, o));
  float ex = (lane < C) ? expf(val - m) : 0.f;
  float s = ex;
#pragma unroll
  for (int o = 32; o > 0; o >>= 1) s += __shfl_xor(s, o);
  float ls = logf(s);
  if (lane < C) out[(size_t)v * C + lane] = val - m - ls;
}

extern "C" void kernel_launch(void* const* d_in, const int* in_sizes, int n_in,
                              void* d_out, int out_size, void* d_ws, size_t ws_size,
                              hipStream_t stream) {
  (void)in_sizes; (void)n_in; (void)out_size; (void)ws_size;
  const float* X = (const float*)d_in[0];
  const int* vertex = (const int*)d_in[1];
  const int* edges = (const int*)d_in[2];
  const float* W1 = (const float*)d_in[3];
  const float* W2 = (const float*)d_in[4];
  const float* Wout = (const float*)d_in[5];
  const float* degE = (const float*)d_in[6];
  const float* degV = (const float*)d_in[7];
  float* out = (float*)d_out;

  char* ws = (char*)d_ws;
  size_t off = 0;
  auto alloc = [&](size_t bytes) -> void* {
    void* p = ws + off;
    off += (bytes + 255) & ~(size_t)255;
    return p;
  };
  bf16* Xb  = (bf16*)alloc((size_t)N_NODES * 512 * sizeof(bf16));
  bf16* Yb  = (bf16*)alloc((size_t)N_NODES * 512 * sizeof(bf16));
  bf16* XeB = (bf16*)alloc((size_t)N_EDGES_C * 512 * sizeof(bf16));
  float* Y40  = (float*)alloc((size_t)N_NODES * 64 * sizeof(float));
  float* Xe40 = (float*)alloc((size_t)N_EDGES_C * 64 * sizeof(float));
  bf16* Wt  = (bf16*)alloc((size_t)512 * 512 * sizeof(bf16));
  int* eoff = (int*)alloc((N_EDGES_C + 1) * sizeof(int));
  int* voff = (int*)alloc((N_NODES + 1) * sizeof(int));
  int* evtx = (int*)alloc((size_t)NNZ_C * sizeof(int));
  int* vedg = (int*)alloc((size_t)NNZ_C * sizeof(int));
  int* cntE = (int*)alloc(N_EDGES_C * sizeof(int));
  int* cntV = (int*)alloc(N_NODES * sizeof(int));
  int* curE = (int*)alloc(N_EDGES_C * sizeof(int));
  int* curV = (int*)alloc(N_NODES * sizeof(int));
  int* partE = (int*)alloc(64 * sizeof(int));
  int* partV = (int*)alloc(64 * sizeof(int));

  hipMemsetAsync(cntE, 0, N_EDGES_C * sizeof(int), stream);
  hipMemsetAsync(cntV, 0, N_NODES * sizeof(int), stream);
  hipMemsetAsync(curE, 0, N_EDGES_C * sizeof(int), stream);
  hipMemsetAsync(curV, 0, N_NODES * sizeof(int), stream);

  hist_kernel<<<(NNZ_C + 255) / 256, 256, 0, stream>>>(vertex, edges, cntV, cntE, NNZ_C);

  const int nbE = (N_EDGES_C + SCHUNK - 1) / SCHUNK;  // 13
  const int nbV = (N_NODES + SCHUNK - 1) / SCHUNK;    // 25
  scan_part<<<nbE, 256, 0, stream>>>(cntE, partE, N_EDGES_C);
  scan_mid<<<1, 64, 0, stream>>>(partE, eoff, nbE, N_EDGES_C);
  scan_final<<<nbE, 256, 0, stream>>>(cntE, partE, eoff, N_EDGES_C);
  scan_part<<<nbV, 256, 0, stream>>>(cntV, partV, N_NODES);
  scan_mid<<<1, 64, 0, stream>>>(partV, voff, nbV, N_NODES);
  scan_final<<<nbV, 256, 0, stream>>>(cntV, partV, voff, N_NODES);

  scatter_kernel<<<(NNZ_C + 255) / 256, 256, 0, stream>>>(vertex, edges, eoff, voff,
                                                          curE, curV, evtx, vedg, NNZ_C);

  convert_f2b<<<(N_NODES * 512 / 4 + 255) / 256, 256, 0, stream>>>(X, Xb, (size_t)N_NODES * 512);

  const int MB = (N_NODES + 127) / 128;

  // ---- layer 1 ----
  transpose_w<<<(512 * 512 + 255) / 256, 256, 0, stream>>>(W1, Wt, 512, 512, 512);
  {
    dim3 g(MB, 4);
    gemm_bf16_kernel<1><<<g, 256, 0, stream>>>(Xb, Wt, nullptr, Yb, N_NODES, 512, 512, 512);
  }
  edge_agg_w<<<(N_EDGES_C + 3) / 4, 256, 0, stream>>>(Yb, eoff, evtx, degE, XeB, N_EDGES_C);
  vtx_agg_w<<<(N_NODES + 3) / 4, 256, 0, stream>>>(XeB, voff, vedg, degV, Xb, N_NODES);

  // ---- layer 2 ----
  transpose_w<<<(512 * 512 + 255) / 256, 256, 0, stream>>>(W2, Wt, 512, 512, 512);
  {
    dim3 g(MB, 4);
    gemm_bf16_kernel<1><<<g, 256, 0, stream>>>(Xb, Wt, nullptr, Yb, N_NODES, 512, 512, 512);
  }
  edge_agg_w<<<(N_EDGES_C + 3) / 4, 256, 0, stream>>>(Yb, eoff, evtx, degE, XeB, N_EDGES_C);
  vtx_agg_w<<<(N_NODES + 3) / 4, 256, 0, stream>>>(XeB, voff, vedg, degV, Xb, N_NODES);

  // ---- layer 3 (C=40) ----
  transpose_w<<<(128 * 512 + 255) / 256, 256, 0, stream>>>(Wout, Wt, 512, 40, 128);
  {
    dim3 g(MB, 1);
    gemm_bf16_kernel<0><<<g, 256, 0, stream>>>(Xb, Wt, Y40, nullptr, N_NODES, 512, 40, 40);
  }
  edge_agg_f32<<<N_EDGES_C, 64, 0, stream>>>(Y40, 40, eoff, evtx, degE, Xe40, 40, 40);
  vtx_agg_lsm<<<N_NODES, 64, 0, stream>>>(Xe40, 40, voff, vedg, degV, out, 40);
}

// Round 6
// 542.621 us; speedup vs baseline: 2.4198x; 1.0437x over previous
//
#include <hip/hip_runtime.h>

#define N_NODES 50000
#define N_EDGES_C 25000
#define NNZ_C 400000
#define SCHUNK 2048

typedef __bf16 bf16;
typedef __bf16 bf16x8 __attribute__((ext_vector_type(8)));
typedef __bf16 bf16x4 __attribute__((ext_vector_type(4)));
typedef float f32x4 __attribute__((ext_vector_type(4)));

typedef __attribute__((address_space(1))) const void as1_cvoid;
typedef __attribute__((address_space(3))) void as3_void;

__device__ __forceinline__ void gload_lds16(const bf16* g, bf16* l) {
  __builtin_amdgcn_global_load_lds((as1_cvoid*)g, (as3_void*)l, 16, 0, 0);
}

// ---------------- CSR build ----------------
__global__ void hist_kernel(const int* __restrict__ vtx, const int* __restrict__ edg,
                            int* __restrict__ cntV, int* __restrict__ cntE, int nnz) {
  int i = blockIdx.x * blockDim.x + threadIdx.x;
  if (i < nnz) {
    atomicAdd(&cntV[vtx[i]], 1);
    atomicAdd(&cntE[edg[i]], 1);
  }
}

__global__ void scan_part(const int* __restrict__ cnt, int* __restrict__ part, int n) {
  __shared__ int red[256];
  const int b = blockIdx.x, t = threadIdx.x;
  const int base = b * SCHUNK + t * 8;
  int s = 0;
#pragma unroll
  for (int q = 0; q < 8; ++q) {
    int i = base + q;
    if (i < n) s += cnt[i];
  }
  red[t] = s;
  __syncthreads();
  for (int d = 128; d > 0; d >>= 1) {
    if (t < d) red[t] += red[t + d];
    __syncthreads();
  }
  if (t == 0) part[b] = red[0];
}

__global__ void scan_mid(int* __restrict__ part, int* __restrict__ off, int nparts, int n) {
  const int lane = threadIdx.x;
  int orig = (lane < nparts) ? part[lane] : 0;
  int v = orig;
  for (int o = 1; o < 64; o <<= 1) {
    int x = __shfl_up(v, o);
    if (lane >= o) v += x;
  }
  if (lane < nparts) part[lane] = v - orig;
  if (lane == 63) off[n] = v;
}

__global__ void scan_final(const int* __restrict__ cnt, const int* __restrict__ part,
                           int* __restrict__ off, int n) {
  __shared__ int tsum[256];
  const int b = blockIdx.x, t = threadIdx.x;
  const int base = b * SCHUNK + t * 8;
  int loc[8];
  int s = 0;
#pragma unroll
  for (int q = 0; q < 8; ++q) {
    int i = base + q;
    loc[q] = (i < n) ? cnt[i] : 0;
    s += loc[q];
  }
  tsum[t] = s;
  __syncthreads();
  for (int d = 1; d < 256; d <<= 1) {
    int x = (t >= d) ? tsum[t - d] : 0;
    __syncthreads();
    tsum[t] += x;
    __syncthreads();
  }
  int run = part[b] + ((t > 0) ? tsum[t - 1] : 0);
#pragma unroll
  for (int q = 0; q < 8; ++q) {
    int i = base + q;
    if (i < n) off[i] = run;
    run += loc[q];
  }
}

__global__ void scatter_kernel(const int* __restrict__ vtx, const int* __restrict__ edg,
                               const int* __restrict__ eoff, const int* __restrict__ voff,
                               int* __restrict__ curE, int* __restrict__ curV,
                               int* __restrict__ evtx, int* __restrict__ vedg, int nnz) {
  int i = blockIdx.x * blockDim.x + threadIdx.x;
  if (i < nnz) {
    int e = edg[i], v = vtx[i];
    int p = atomicAdd(&curE[e], 1);
    evtx[eoff[e] + p] = v;
    int q = atomicAdd(&curV[v], 1);
    vedg[voff[v] + q] = e;
  }
}

// ---------------- conversions ----------------
__global__ void convert_f2b(const float* __restrict__ in, bf16* __restrict__ out, size_t n) {
  size_t i = ((size_t)blockIdx.x * blockDim.x + threadIdx.x) * 4;
  if (i >= n) return;
  float4 v = *(const float4*)(in + i);
  bf16x4 o;
  o[0] = (bf16)v.x; o[1] = (bf16)v.y; o[2] = (bf16)v.z; o[3] = (bf16)v.w;
  *(bf16x4*)(out + i) = o;
}

__global__ void transpose_w(const float* __restrict__ W, bf16* __restrict__ Wt,
                            int K, int N, int NtRows) {
  int idx = blockIdx.x * blockDim.x + threadIdx.x;
  int total = NtRows * K;
  if (idx >= total) return;
  int n = idx / K;
  int k = idx - n * K;
  Wt[idx] = (n < N) ? (bf16)W[(size_t)k * N + n] : (bf16)0.0f;
}

// ---------------- GEMM: BK=64, swizzled LDS ----------------
// LDS row = 64 bf16 = 128B (full bank wrap).  16B chunk c of row r is stored
// at physical slot c^(r&7); gload_lds writes linearly so the GLOBAL source
// address carries the inverse permutation (same involution).  ds_read_b128
// applies the same XOR -> every 8-lane group hits all 8 bank quads.
template <int BF16OUT>
__global__ __launch_bounds__(256) void gemm_bf16_kernel(
    const bf16* __restrict__ A, const bf16* __restrict__ B,
    float* __restrict__ Cf, bf16* __restrict__ Cb, int M, int K, int ldC, int Nstore) {
  __shared__ bf16 Al[128][64];
  __shared__ bf16 Bl[128][64];
  const int t = threadIdx.x;
  const int m0 = blockIdx.x * 128;
  const int n0 = blockIdx.y * 128;
  const int w = t >> 6, lane = t & 63;
  const int wr = w >> 1, wc = w & 1;
  const int lr = lane & 15;       // fragment row within 16
  const int ls = lane >> 4;       // logical 16B chunk index (0..3) within 32-elem half

  f32x4 acc[4][4];
#pragma unroll
  for (int m = 0; m < 4; ++m)
#pragma unroll
    for (int n = 0; n < 4; ++n) acc[m][n] = (f32x4){0.f, 0.f, 0.f, 0.f};

  // staging: wave covers 32 rows per k-step in 4 issues of 8 rows
  const int srow = lane >> 3;                                   // 0..7
  const int scol = ((lane & 7) ^ ((lane >> 3) & 7)) << 3;       // swizzled elem offset

  for (int kk = 0; kk < K; kk += 64) {
#pragma unroll
    for (int q = 0; q < 4; ++q) {
      const int row = w * 32 + q * 8 + srow;
      gload_lds16(A + (size_t)(m0 + row) * K + kk + scol, &Al[w * 32 + q * 8][0]);
      gload_lds16(B + (size_t)(n0 + row) * K + kk + scol, &Bl[w * 32 + q * 8][0]);
    }
    __syncthreads();
#pragma unroll
    for (int ks = 0; ks < 2; ++ks) {
      bf16x8 af[4], bfr[4];
#pragma unroll
      for (int m = 0; m < 4; ++m) {
        const int R = wr * 64 + m * 16 + lr;
        af[m] = *(const bf16x8*)(&Al[R][((ks * 4 + ls) ^ (lr & 7)) << 3]);
      }
#pragma unroll
      for (int n = 0; n < 4; ++n) {
        const int R = wc * 64 + n * 16 + lr;
        bfr[n] = *(const bf16x8*)(&Bl[R][((ks * 4 + ls) ^ (lr & 7)) << 3]);
      }
#pragma unroll
      for (int m = 0; m < 4; ++m)
#pragma unroll
        for (int n = 0; n < 4; ++n)
          acc[m][n] = __builtin_amdgcn_mfma_f32_16x16x32_bf16(af[m], bfr[n], acc[m][n], 0, 0, 0);
    }
    __syncthreads();
  }

  const int cr = (lane >> 4) << 2;  // C/D: col = lane&15, row = (lane>>4)*4 + i
  const int cc = lane & 15;
#pragma unroll
  for (int m = 0; m < 4; ++m) {
#pragma unroll
    for (int n = 0; n < 4; ++n) {
      int gc = n0 + wc * 64 + n * 16 + cc;
      if (gc >= Nstore) continue;
#pragma unroll
      for (int i = 0; i < 4; ++i) {
        int gr = m0 + wr * 64 + m * 16 + cr + i;
        if (gr < M) {
          if (BF16OUT) Cb[(size_t)gr * ldC + gc] = (bf16)acc[m][n][i];
          else         Cf[(size_t)gr * ldC + gc] = acc[m][n][i];
        }
      }
    }
  }
}

// ---------------- wave-per-edge aggregation (bf16, C=512), unroll-4 ----------------
__global__ __launch_bounds__(256) void edge_agg_w(
    const bf16* __restrict__ Y, const int* __restrict__ eoff, const int* __restrict__ evtx,
    const float* __restrict__ degE, bf16* __restrict__ Xe, int nE) {
  const int wv = (blockIdx.x * 256 + threadIdx.x) >> 6;
  if (wv >= nE) return;
  const int lane = threadIdx.x & 63;
  const int beg = eoff[wv], end = eoff[wv + 1];
  const int cnt = end - beg;
  const float scale = (cnt > 0) ? degE[wv] / (float)cnt : 0.f;
  float acc[8] = {0.f, 0.f, 0.f, 0.f, 0.f, 0.f, 0.f, 0.f};
  for (int base = beg; base < end; base += 64) {
    const int nb = min(64, end - base);
    int myidx = (lane < nb) ? evtx[base + lane] : 0;
    int j = 0;
    for (; j + 3 < nb; j += 4) {
      const int i0 = __shfl(myidx, j);
      const int i1 = __shfl(myidx, j + 1);
      const int i2 = __shfl(myidx, j + 2);
      const int i3 = __shfl(myidx, j + 3);
      bf16x8 v0 = *(const bf16x8*)(Y + (size_t)i0 * 512 + lane * 8);
      bf16x8 v1 = *(const bf16x8*)(Y + (size_t)i1 * 512 + lane * 8);
      bf16x8 v2 = *(const bf16x8*)(Y + (size_t)i2 * 512 + lane * 8);
      bf16x8 v3 = *(const bf16x8*)(Y + (size_t)i3 * 512 + lane * 8);
#pragma unroll
      for (int q = 0; q < 8; ++q)
        acc[q] += ((float)v0[q] + (float)v1[q]) + ((float)v2[q] + (float)v3[q]);
    }
    for (; j < nb; ++j) {
      const int i0 = __shfl(myidx, j);
      bf16x8 v0 = *(const bf16x8*)(Y + (size_t)i0 * 512 + lane * 8);
#pragma unroll
      for (int q = 0; q < 8; ++q) acc[q] += (float)v0[q];
    }
  }
  bf16x8 o;
#pragma unroll
  for (int q = 0; q < 8; ++q) o[q] = (bf16)(acc[q] * scale);
  *(bf16x8*)(Xe + (size_t)wv * 512 + lane * 8) = o;
}

// ---------------- wave-per-vertex aggregation (bf16, relu, C=512), unroll-4 ----------------
__global__ __launch_bounds__(256) void vtx_agg_w(
    const bf16* __restrict__ Xe, const int* __restrict__ voff, const int* __restrict__ vedg,
    const float* __restrict__ degV, bf16* __restrict__ outB, int nV) {
  const int wv = (blockIdx.x * 256 + threadIdx.x) >> 6;
  if (wv >= nV) return;
  const int lane = threadIdx.x & 63;
  const int beg = voff[wv], end = voff[wv + 1];
  const float dv = degV[wv];
  float acc[8] = {0.f, 0.f, 0.f, 0.f, 0.f, 0.f, 0.f, 0.f};
  for (int base = beg; base < end; base += 64) {
    const int nb = min(64, end - base);
    int myidx = (lane < nb) ? vedg[base + lane] : 0;
    int j = 0;
    for (; j + 3 < nb; j += 4) {
      const int i0 = __shfl(myidx, j);
      const int i1 = __shfl(myidx, j + 1);
      const int i2 = __shfl(myidx, j + 2);
      const int i3 = __shfl(myidx, j + 3);
      bf16x8 v0 = *(const bf16x8*)(Xe + (size_t)i0 * 512 + lane * 8);
      bf16x8 v1 = *(const bf16x8*)(Xe + (size_t)i1 * 512 + lane * 8);
      bf16x8 v2 = *(const bf16x8*)(Xe + (size_t)i2 * 512 + lane * 8);
      bf16x8 v3 = *(const bf16x8*)(Xe + (size_t)i3 * 512 + lane * 8);
#pragma unroll
      for (int q = 0; q < 8; ++q)
        acc[q] += ((float)v0[q] + (float)v1[q]) + ((float)v2[q] + (float)v3[q]);
    }
    for (; j < nb; ++j) {
      const int i0 = __shfl(myidx, j);
      bf16x8 v0 = *(const bf16x8*)(Xe + (size_t)i0 * 512 + lane * 8);
#pragma unroll
      for (int q = 0; q < 8; ++q) acc[q] += (float)v0[q];
    }
  }
  bf16x8 o;
#pragma unroll
  for (int q = 0; q < 8; ++q) o[q] = (bf16)fmaxf(acc[q] * dv, 0.f);
  *(bf16x8*)(outB + (size_t)wv * 512 + lane * 8) = o;
}

// ---------------- wave-per-edge aggregation f32 (layer 3, C=40) ----------------
__global__ __launch_bounds__(256) void edge_agg40_w(
    const float* __restrict__ Y, const int* __restrict__ eoff, const int* __restrict__ evtx,
    const float* __restrict__ degE, float* __restrict__ Xe, int nE) {
  const int wv = (blockIdx.x * 256 + threadIdx.x) >> 6;
  if (wv >= nE) return;
  const int lane = threadIdx.x & 63;
  const int beg = eoff[wv], end = eoff[wv + 1];
  const int cnt = end - beg;
  const float scale = (cnt > 0) ? degE[wv] / (float)cnt : 0.f;
  float a0 = 0.f;
  for (int base = beg; base < end; base += 64) {
    const int nb = min(64, end - base);
    int myidx = (lane < nb) ? evtx[base + lane] : 0;
    int j = 0;
    for (; j + 3 < nb; j += 4) {
      const int i0 = __shfl(myidx, j);
      const int i1 = __shfl(myidx, j + 1);
      const int i2 = __shfl(myidx, j + 2);
      const int i3 = __shfl(myidx, j + 3);
      if (lane < 40) {
        float x0 = Y[(size_t)i0 * 40 + lane];
        float x1 = Y[(size_t)i1 * 40 + lane];
        float x2 = Y[(size_t)i2 * 40 + lane];
        float x3 = Y[(size_t)i3 * 40 + lane];
        a0 += (x0 + x1) + (x2 + x3);
      }
    }
    for (; j < nb; ++j) {
      const int i0 = __shfl(myidx, j);
      if (lane < 40) a0 += Y[(size_t)i0 * 40 + lane];
    }
  }
  if (lane < 40) Xe[(size_t)wv * 40 + lane] = a0 * scale;
}

// ---------------- final vertex aggregation + log_softmax (C=40, wave-per-vertex) ----------------
__global__ __launch_bounds__(256) void vtx_agg_lsm(
    const float* __restrict__ Xe, const int* __restrict__ voff, const int* __restrict__ vedg,
    const float* __restrict__ degV, float* __restrict__ out, int nV) {
  const int wv = (blockIdx.x * 256 + threadIdx.x) >> 6;
  if (wv >= nV) return;
  const int lane = threadIdx.x & 63;
  const int beg = voff[wv], end = voff[wv + 1];
  const float dv = degV[wv];
  float a0 = 0.f;
  for (int base = beg; base < end; base += 64) {
    const int nb = min(64, end - base);
    int myidx = (lane < nb) ? vedg[base + lane] : 0;
    int j = 0;
    for (; j + 3 < nb; j += 4) {
      const int i0 = __shfl(myidx, j);
      const int i1 = __shfl(myidx, j + 1);
      const int i2 = __shfl(myidx, j + 2);
      const int i3 = __shfl(myidx, j + 3);
      if (lane < 40) {
        float x0 = Xe[(size_t)i0 * 40 + lane];
        float x1 = Xe[(size_t)i1 * 40 + lane];
        float x2 = Xe[(size_t)i2 * 40 + lane];
        float x3 = Xe[(size_t)i3 * 40 + lane];
        a0 += (x0 + x1) + (x2 + x3);
      }
    }
    for (; j < nb; ++j) {
      const int i0 = __shfl(myidx, j);
      if (lane < 40) a0 += Xe[(size_t)i0 * 40 + lane];
    }
  }
  a0 *= dv;
  float val = (lane < 40) ? a0 : -3.4e38f;
  float m = val;
#pragma unroll
  for (int o = 32; o > 0; o >>= 1) m = fmaxf(m, __shfl_xor(m, o));
  float ex = (lane < 40) ? expf(val - m) : 0.f;
  float s = ex;
#pragma unroll
  for (int o = 32; o > 0; o >>= 1) s += __shfl_xor(s, o);
  float ls = logf(s);
  if (lane < 40) out[(size_t)wv * 40 + lane] = val - m - ls;
}

extern "C" void kernel_launch(void* const* d_in, const int* in_sizes, int n_in,
                              void* d_out, int out_size, void* d_ws, size_t ws_size,
                              hipStream_t stream) {
  (void)in_sizes; (void)n_in; (void)out_size; (void)ws_size;
  const float* X = (const float*)d_in[0];
  const int* vertex = (const int*)d_in[1];
  const int* edges = (const int*)d_in[2];
  const float* W1 = (const float*)d_in[3];
  const float* W2 = (const float*)d_in[4];
  const float* Wout = (const float*)d_in[5];
  const float* degE = (const float*)d_in[6];
  const float* degV = (const float*)d_in[7];
  float* out = (float*)d_out;

  char* ws = (char*)d_ws;
  size_t off = 0;
  auto alloc = [&](size_t bytes) -> void* {
    void* p = ws + off;
    off += (bytes + 255) & ~(size_t)255;
    return p;
  };
  bf16* Xb  = (bf16*)alloc((size_t)N_NODES * 512 * sizeof(bf16));
  bf16* Yb  = (bf16*)alloc((size_t)N_NODES * 512 * sizeof(bf16));
  bf16* XeB = (bf16*)alloc((size_t)N_EDGES_C * 512 * sizeof(bf16));
  float* Y40  = (float*)alloc((size_t)N_NODES * 40 * sizeof(float));
  float* Xe40 = (float*)alloc((size_t)N_EDGES_C * 40 * sizeof(float));
  bf16* Wt  = (bf16*)alloc((size_t)512 * 512 * sizeof(bf16));
  int* eoff = (int*)alloc((N_EDGES_C + 1) * sizeof(int));
  int* voff = (int*)alloc((N_NODES + 1) * sizeof(int));
  int* evtx = (int*)alloc((size_t)NNZ_C * sizeof(int));
  int* vedg = (int*)alloc((size_t)NNZ_C * sizeof(int));
  int* cntE = (int*)alloc(N_EDGES_C * sizeof(int));
  int* cntV = (int*)alloc(N_NODES * sizeof(int));
  int* curE = (int*)alloc(N_EDGES_C * sizeof(int));
  int* curV = (int*)alloc(N_NODES * sizeof(int));
  int* partE = (int*)alloc(64 * sizeof(int));
  int* partV = (int*)alloc(64 * sizeof(int));

  hipMemsetAsync(cntE, 0, N_EDGES_C * sizeof(int), stream);
  hipMemsetAsync(cntV, 0, N_NODES * sizeof(int), stream);
  hipMemsetAsync(curE, 0, N_EDGES_C * sizeof(int), stream);
  hipMemsetAsync(curV, 0, N_NODES * sizeof(int), stream);

  hist_kernel<<<(NNZ_C + 255) / 256, 256, 0, stream>>>(vertex, edges, cntV, cntE, NNZ_C);

  const int nbE = (N_EDGES_C + SCHUNK - 1) / SCHUNK;
  const int nbV = (N_NODES + SCHUNK - 1) / SCHUNK;
  scan_part<<<nbE, 256, 0, stream>>>(cntE, partE, N_EDGES_C);
  scan_mid<<<1, 64, 0, stream>>>(partE, eoff, nbE, N_EDGES_C);
  scan_final<<<nbE, 256, 0, stream>>>(cntE, partE, eoff, N_EDGES_C);
  scan_part<<<nbV, 256, 0, stream>>>(cntV, partV, N_NODES);
  scan_mid<<<1, 64, 0, stream>>>(partV, voff, nbV, N_NODES);
  scan_final<<<nbV, 256, 0, stream>>>(cntV, partV, voff, N_NODES);

  scatter_kernel<<<(NNZ_C + 255) / 256, 256, 0, stream>>>(vertex, edges, eoff, voff,
                                                          curE, curV, evtx, vedg, NNZ_C);

  convert_f2b<<<(N_NODES * 512 / 4 + 255) / 256, 256, 0, stream>>>(X, Xb, (size_t)N_NODES * 512);

  const int MB = (N_NODES + 127) / 128;

  // ---- layer 1 ----
  transpose_w<<<(512 * 512 + 255) / 256, 256, 0, stream>>>(W1, Wt, 512, 512, 512);
  {
    dim3 g(MB, 4);
    gemm_bf16_kernel<1><<<g, 256, 0, stream>>>(Xb, Wt, nullptr, Yb, N_NODES, 512, 512, 512);
  }
  edge_agg_w<<<(N_EDGES_C + 3) / 4, 256, 0, stream>>>(Yb, eoff, evtx, degE, XeB, N_EDGES_C);
  vtx_agg_w<<<(N_NODES + 3) / 4, 256, 0, stream>>>(XeB, voff, vedg, degV, Xb, N_NODES);

  // ---- layer 2 ----
  transpose_w<<<(512 * 512 + 255) / 256, 256, 0, stream>>>(W2, Wt, 512, 512, 512);
  {
    dim3 g(MB, 4);
    gemm_bf16_kernel<1><<<g, 256, 0, stream>>>(Xb, Wt, nullptr, Yb, N_NODES, 512, 512, 512);
  }
  edge_agg_w<<<(N_EDGES_C + 3) / 4, 256, 0, stream>>>(Yb, eoff, evtx, degE, XeB, N_EDGES_C);
  vtx_agg_w<<<(N_NODES + 3) / 4, 256, 0, stream>>>(XeB, voff, vedg, degV, Xb, N_NODES);

  // ---- layer 3 (C=40) ----
  transpose_w<<<(128 * 512 + 255) / 256, 256, 0, stream>>>(Wout, Wt, 512, 40, 128);
  {
    dim3 g(MB, 1);
    gemm_bf16_kernel<0><<<g, 256, 0, stream>>>(Xb, Wt, Y40, nullptr, N_NODES, 512, 40, 40);
  }
  edge_agg40_w<<<(N_EDGES_C + 3) / 4, 256, 0, stream>>>(Y40, eoff, evtx, degE, Xe40, N_EDGES_C);
  vtx_agg_lsm<<<(N_NODES + 3) / 4, 256, 0, stream>>>(Xe40, voff, vedg, degV, out, N_NODES);
}